// Round 4
// baseline (942.324 us; speedup 1.0000x reference)
//
#include <hip/hip_runtime.h>
#include <hip/hip_cooperative_groups.h>
#include <math.h>

namespace cg = cooperative_groups;

// ---------------------------------------------------------------------------
// Round 3: gate-split across blocks to beat the per-CU L1 W-stream bound.
//  - 96 blocks x 1024 threads: (rg = bid&31) row-group of 16 rows,
//    (gate = bid>>5) in {r,z,n}. Each block streams only its gate's W slice
//    (262 KB hi+lo per eval, vs 786 KB before -> 3x less L1 fill).
//  - Per eval: pack ys -> A-frags (LDS); 16 waves x 1 n-tile x 8 ksteps x 3
//    split-products MFMA; write g-slice (16x256 f32) to global exchange
//    buffer gx[parity]; grid.sync; read all 3 gate slices; nonlinearity ->
//    full k vector computed redundantly (bitwise identical) in every block.
//  - Double-buffered gx by eval parity => 1 grid.sync per eval.
//  - Math is bit-for-bit identical to round 2 (same fragments, same MFMA
//    chain order, same controller) -> expect absmax == 0.0078125 exactly.
//  - Fallback: if ws_size < 4.13 MB, launch the round-2 kernel (passed).
//
// ws layout (bytes):
//   [0,393216)        Wb_hi  ushort[196608]  B-frag-packed bf16 hi of Wih[:,:256]
//   [393216,786432)   Wb_lo  ushort[196608]  bf16 lo
//   [786432,917504)   Wpt    float[32768]    Wp transpose
//   [917504,983040)   Wlt    float[16384]    Wl transpose
//   [983040,983552)   partials double[2][32]
//   [983552,4129280)  gx     float[2][32][3][16][256]  (gate-split only)
// ---------------------------------------------------------------------------

typedef __attribute__((ext_vector_type(8))) short bf16x8s;
typedef __attribute__((ext_vector_type(4))) float f32x4;

#define F(x) ((float)(x))

static __device__ __forceinline__ unsigned short f2bf(float f) {
  unsigned u = __float_as_uint(f);
  unsigned r = (u + 0x7FFFu + ((u >> 16) & 1u)) >> 16;
  return (unsigned short)r;
}
static __device__ __forceinline__ float bf2f(unsigned short b) {
  return __uint_as_float(((unsigned)b) << 16);
}
static __device__ __forceinline__ float sigm(float x) {
  return 1.0f / (1.0f + __expf(-x));
}
static __device__ __forceinline__ float tanh_fast(float x) {
  float e = __expf(-2.0f * fabsf(x));
  float t = (1.0f - e) / (1.0f + e);
  return copysignf(t, x);
}

__global__ void prep_kernel(const float* __restrict__ Wih,
                            const float* __restrict__ Wp,
                            const float* __restrict__ Wl,
                            float* __restrict__ ws) {
  int i = blockIdx.x * blockDim.x + threadIdx.x;
  if (i < 196608) {
    const int j = i & 7, l = (i >> 3) & 63, ks = (i >> 9) & 7, nt = i >> 12;
    const int c = nt * 16 + (l & 15);          // gate-output column
    const int k = ks * 32 + (l >> 4) * 8 + j;  // k index (same perm as A)
    const float f = Wih[c * 257 + k];
    unsigned short hi = f2bf(f);
    unsigned short lo = f2bf(f - bf2f(hi));
    ((unsigned short*)ws)[i] = hi;
    ((unsigned short*)ws)[196608 + i] = lo;
  } else if (i < 229376) {
    int ii = i - 196608; int hh = ii & 255, k = ii >> 8;
    ws[i] = Wp[hh * 128 + k];
  } else if (i < 245760) {
    int ii = i - 229376; int c = ii & 63, k = ii >> 6;
    ws[i] = Wl[c * 256 + k];
  }
}

// ============================ gate-split kernel ============================
// LDS float offsets
#define GS_YH 0      // ushort[4096] (aliased: x-staging at init, y at end)
#define GS_YL 2048   // ushort[4096]
#define GS_CR0 4096
#define GS_CZ0 4352
#define GS_BN 4608
#define GS_WTR 4864
#define GS_WTZ 5120
#define GS_WTN 5376
#define GS_BHN 5632
#define GS_RED 5888  // 16 doubles
#define GS_SB 5920   // 1 double

__device__ __forceinline__ void eval_gs(
    cg::grid_group& grid, float* __restrict__ smem,
    const unsigned short* __restrict__ wbh,
    const unsigned short* __restrict__ wbl,
    float* __restrict__ gx,
    int rg, int gate, int lane, int row, int h0, int fo, int ntile,
    int par, const float ys[4], float ts_, float kout[4]) {
  // ---- pack ys -> A-frags (bf16 hi/lo), consistent k-perm ----
  unsigned short h_[4], l_[4];
#pragma unroll
  for (int c = 0; c < 4; ++c) {
    h_[c] = f2bf(ys[c]);
    l_[c] = f2bf(ys[c] - bf2f(h_[c]));
  }
  unsigned short* yhb = (unsigned short*)smem;
  *(ushort4*)(yhb + fo) = make_ushort4(h_[0], h_[1], h_[2], h_[3]);
  *(ushort4*)(yhb + 4096 + fo) = make_ushort4(l_[0], l_[1], l_[2], l_[3]);
  __syncthreads();

  // ---- GEMM: 1 n-tile per wave, K=256 in 8 steps, 3 split-products ----
  f32x4 ac = {0.f, 0.f, 0.f, 0.f};
  const unsigned short* yh = yhb;
  const unsigned short* yl = yhb + 4096;
#pragma unroll
  for (int ks2 = 0; ks2 < 8; ++ks2) {
    const bf16x8s ah = *(const bf16x8s*)(yh + (ks2 * 64 + lane) * 8);
    const bf16x8s al = *(const bf16x8s*)(yl + (ks2 * 64 + lane) * 8);
    const bf16x8s bh = *(const bf16x8s*)(wbh + ((ntile * 8 + ks2) * 64 + lane) * 8);
    const bf16x8s blo = *(const bf16x8s*)(wbl + ((ntile * 8 + ks2) * 64 + lane) * 8);
    ac = __builtin_amdgcn_mfma_f32_16x16x32_bf16(al, bh, ac, 0, 0, 0);
    ac = __builtin_amdgcn_mfma_f32_16x16x32_bf16(ah, blo, ac, 0, 0, 0);
    ac = __builtin_amdgcn_mfma_f32_16x16x32_bf16(ah, bh, ac, 0, 0, 0);
  }
  // ---- C write to global exchange: col=lane&15, row=(lane>>4)*4+j ----
  {
    float* gslot = gx + (size_t)((par * 32 + rg) * 3 + gate) * 4096;
    const int gcol = (ntile & 15) * 16 + (lane & 15);  // local col within gate
    const int gr0 = (lane >> 4) * 4;
#pragma unroll
    for (int j = 0; j < 4; ++j) gslot[(gr0 + j) * 256 + gcol] = ac[j];
  }
  grid.sync();

  // ---- read all 3 gate slices for owned elements (row, h0..h0+3) ----
  const float* gbase = gx + (size_t)(par * 32 + rg) * 3 * 4096;
  const float4 gR = *(const float4*)(gbase + 0 * 4096 + row * 256 + h0);
  const float4 gZ = *(const float4*)(gbase + 1 * 4096 + row * 256 + h0);
  const float4 gN = *(const float4*)(gbase + 2 * 4096 + row * 256 + h0);
  float gRa[4] = {gR.x, gR.y, gR.z, gR.w};
  float gZa[4] = {gZ.x, gZ.y, gZ.z, gZ.w};
  float gNa[4] = {gN.x, gN.y, gN.z, gN.w};
  float cra[4], cza[4], bna[4], wra[4], wza[4], wna[4], bha[4];
  {
    float4 tv;
    tv = *(const float4*)(smem + GS_CR0 + h0); cra[0]=tv.x; cra[1]=tv.y; cra[2]=tv.z; cra[3]=tv.w;
    tv = *(const float4*)(smem + GS_CZ0 + h0); cza[0]=tv.x; cza[1]=tv.y; cza[2]=tv.z; cza[3]=tv.w;
    tv = *(const float4*)(smem + GS_BN + h0);  bna[0]=tv.x; bna[1]=tv.y; bna[2]=tv.z; bna[3]=tv.w;
    tv = *(const float4*)(smem + GS_WTR + h0); wra[0]=tv.x; wra[1]=tv.y; wra[2]=tv.z; wra[3]=tv.w;
    tv = *(const float4*)(smem + GS_WTZ + h0); wza[0]=tv.x; wza[1]=tv.y; wza[2]=tv.z; wza[3]=tv.w;
    tv = *(const float4*)(smem + GS_WTN + h0); wna[0]=tv.x; wna[1]=tv.y; wna[2]=tv.z; wna[3]=tv.w;
    tv = *(const float4*)(smem + GS_BHN + h0); bha[0]=tv.x; bha[1]=tv.y; bha[2]=tv.z; bha[3]=tv.w;
  }
#pragma unroll
  for (int c = 0; c < 4; ++c) {
    const float rv = sigm(gRa[c] + cra[c] + ts_ * wra[c]);
    const float zv = sigm(gZa[c] + cza[c] + ts_ * wza[c]);
    const float nv = tanh_fast(gNa[c] + bna[c] + ts_ * wna[c] + rv * bha[c]);
    kout[c] = (1.0f - zv) * nv;
  }
}

__global__ void __launch_bounds__(1024)
ode_gs(const float* __restrict__ x,
       const float* __restrict__ tp, int nt,
       const float* __restrict__ bp,
       const float* __restrict__ Wih,
       const float* __restrict__ bih,
       const float* __restrict__ bhh,
       const float* __restrict__ bl,
       const float* __restrict__ ws_f,
       float* __restrict__ gx,
       double* __restrict__ partials,
       float* __restrict__ out) {
  extern __shared__ float smem[];
  cg::grid_group grid = cg::this_grid();

  const int bid = blockIdx.x;
  const int rg = bid & 31;       // rows rg*16 .. rg*16+15
  const int gate = bid >> 5;     // 0=r, 1=z, 2=n
  const int t = threadIdx.x;
  const int lane = t & 63;
  const int w = t >> 6;          // wave = owned row
  const int row = w;
  const int h0 = lane * 4;
  const int ntile = gate * 16 + w;  // this wave's n-tile (global)
  const int fo = ((h0 >> 5) * 64 + row + ((h0 >> 3) & 3) * 16) * 8 + (h0 & 7);

  const unsigned short* wbh = (const unsigned short*)ws_f;
  const unsigned short* wbl = ((const unsigned short*)ws_f) + 196608;
  const float* Wpt = ws_f + 196608;
  const float* Wlt = ws_f + 229376;

  const float t0 = tp[0];
  const float t1v = tp[nt - 1];

  // ---- stage per-h constants into LDS ----
  if (t < 256) {
    smem[GS_CR0 + t] = bih[t] + bhh[t];
    smem[GS_CZ0 + t] = bih[256 + t] + bhh[256 + t];
    smem[GS_BN + t]  = bih[512 + t];
    smem[GS_BHN + t] = bhh[512 + t];
    smem[GS_WTR + t] = Wih[t * 257 + 256];
    smem[GS_WTZ + t] = Wih[(256 + t) * 257 + 256];
    smem[GS_WTN + t] = Wih[(512 + t) * 257 + 256];
  }
  // ---- stage x (16 rows x 128) into frag area (aliased) ----
  if (t < 2048) {  // always true; 2 elems/thread
    smem[t] = x[(rg * 16 + (t >> 7)) * 128 + (t & 127)];
    const int i2 = t + 1024;
    smem[i2] = x[(rg * 16 + (i2 >> 7)) * 128 + (i2 & 127)];
  }
  __syncthreads();

  // ---- h0 = x @ Wp.T + bp ----
  float yb[4];
  {
    float acc[4] = {0.f, 0.f, 0.f, 0.f};
    for (int k = 0; k < 128; ++k) {
      const float xv = smem[row * 128 + k];
      const float4 wv4 = *(const float4*)(Wpt + k * 256 + h0);
      acc[0] = fmaf(xv, wv4.x, acc[0]);
      acc[1] = fmaf(xv, wv4.y, acc[1]);
      acc[2] = fmaf(xv, wv4.z, acc[2]);
      acc[3] = fmaf(xv, wv4.w, acc[3]);
    }
    const float4 bp4 = *(const float4*)(bp + h0);
    yb[0] = acc[0] + bp4.x; yb[1] = acc[1] + bp4.y;
    yb[2] = acc[2] + bp4.z; yb[3] = acc[3] + bp4.w;
  }
  __syncthreads();  // x-staging region about to be overwritten by A-frags

  float tcur = t0;
  float dt = (t1v - t0) * 0.01f + 1e-8f;
  int ec = 0;  // eval counter (gx parity)

  float k1v[4], k2v[4], k3v[4], k4v[4], k5v[4], k6v[4], k7v[4];
  float ys[4];

#pragma unroll
  for (int c = 0; c < 4; ++c) ys[c] = yb[c];
  eval_gs(grid, smem, wbh, wbl, gx, rg, gate, lane, row, h0, fo, ntile,
          ec & 1, ys, t0, k1v);
  ++ec;

  for (int step = 0; step < 64; ++step) {
    if (t1v - tcur <= 1e-6f) break;  // exact: ref freezes state once done
    const float dtc = fminf(dt, t1v - tcur);

#pragma unroll
    for (int c = 0; c < 4; ++c) ys[c] = fmaf(dtc * 0.2f, k1v[c], yb[c]);
    eval_gs(grid, smem, wbh, wbl, gx, rg, gate, lane, row, h0, fo, ntile,
            ec & 1, ys, tcur + dtc * 0.2f, k2v);
    ++ec;

#pragma unroll
    for (int c = 0; c < 4; ++c)
      ys[c] = fmaf(dtc, fmaf(F(9.0/40.0), k2v[c], F(3.0/40.0) * k1v[c]), yb[c]);
    eval_gs(grid, smem, wbh, wbl, gx, rg, gate, lane, row, h0, fo, ntile,
            ec & 1, ys, tcur + dtc * 0.3f, k3v);
    ++ec;

#pragma unroll
    for (int c = 0; c < 4; ++c) {
      float in_ = F(44.0/45.0) * k1v[c];
      in_ = fmaf(F(-56.0/15.0), k2v[c], in_);
      in_ = fmaf(F(32.0/9.0), k3v[c], in_);
      ys[c] = fmaf(dtc, in_, yb[c]);
    }
    eval_gs(grid, smem, wbh, wbl, gx, rg, gate, lane, row, h0, fo, ntile,
            ec & 1, ys, tcur + dtc * 0.8f, k4v);
    ++ec;

#pragma unroll
    for (int c = 0; c < 4; ++c) {
      float in_ = F(19372.0/6561.0) * k1v[c];
      in_ = fmaf(F(-25360.0/2187.0), k2v[c], in_);
      in_ = fmaf(F(64448.0/6561.0), k3v[c], in_);
      in_ = fmaf(F(-212.0/729.0), k4v[c], in_);
      ys[c] = fmaf(dtc, in_, yb[c]);
    }
    eval_gs(grid, smem, wbh, wbl, gx, rg, gate, lane, row, h0, fo, ntile,
            ec & 1, ys, tcur + dtc * F(8.0/9.0), k5v);
    ++ec;

#pragma unroll
    for (int c = 0; c < 4; ++c) {
      float in_ = F(9017.0/3168.0) * k1v[c];
      in_ = fmaf(F(-355.0/33.0), k2v[c], in_);
      in_ = fmaf(F(46732.0/5247.0), k3v[c], in_);
      in_ = fmaf(F(49.0/176.0), k4v[c], in_);
      in_ = fmaf(F(-5103.0/18656.0), k5v[c], in_);
      ys[c] = fmaf(dtc, in_, yb[c]);
    }
    eval_gs(grid, smem, wbh, wbl, gx, rg, gate, lane, row, h0, fo, ntile,
            ec & 1, ys, tcur + dtc, k6v);
    ++ec;

    // y5 into ys, k7 = f(t+dt, y5)
#pragma unroll
    for (int c = 0; c < 4; ++c) {
      float in_ = F(35.0/384.0) * k1v[c];
      in_ = fmaf(F(500.0/1113.0), k3v[c], in_);
      in_ = fmaf(F(125.0/192.0), k4v[c], in_);
      in_ = fmaf(F(-2187.0/6784.0), k5v[c], in_);
      in_ = fmaf(F(11.0/84.0), k6v[c], in_);
      ys[c] = fmaf(dtc, in_, yb[c]);
    }
    eval_gs(grid, smem, wbh, wbl, gx, rg, gate, lane, row, h0, fo, ntile,
            ec & 1, ys, tcur + dtc, k7v);
    ++ec;

    // ---- error estimate over thread-owned elements ----
    double lsum = 0.0;
#pragma unroll
    for (int c = 0; c < 4; ++c) {
      float ev = F(71.0/57600.0) * k1v[c];
      ev = fmaf(F(-71.0/16695.0), k3v[c], ev);
      ev = fmaf(F(71.0/1920.0), k4v[c], ev);
      ev = fmaf(F(-17253.0/339200.0), k5v[c], ev);
      ev = fmaf(F(22.0/525.0), k6v[c], ev);
      ev = fmaf(F(-1.0/40.0), k7v[c], ev);
      ev *= dtc;
      const float sc = 1e-6f + 1e-5f * fmaxf(fabsf(yb[c]), fabsf(ys[c]));
      const float qq = ev / sc;
      lsum += (double)(qq * qq);
    }
    double v = lsum;
#pragma unroll
    for (int d = 1; d < 64; d <<= 1) v += __shfl_xor(v, d, 64);
    if (lane == 0) ((double*)(smem + GS_RED))[w] = v;
    __syncthreads();
    if (w == 0 && gate == 0) {
      double v2 = (lane < 16) ? ((double*)(smem + GS_RED))[lane] : 0.0;
#pragma unroll
      for (int d = 1; d < 64; d <<= 1) v2 += __shfl_xor(v2, d, 64);
      if (lane == 0) partials[(step & 1) * 32 + rg] = v2;
    }
    grid.sync();
    if (w == 0) {
      double v3 = (lane < 32) ? partials[(step & 1) * 32 + lane] : 0.0;
#pragma unroll
      for (int d = 1; d < 64; d <<= 1) v3 += __shfl_xor(v3, d, 64);
      if (lane == 0) ((double*)(smem + GS_SB))[0] = v3;
    }
    __syncthreads();
    const double sb = ((double*)(smem + GS_SB))[0];
    const float err_norm = sqrtf((float)(sb / 131072.0));
    const bool accept = (err_norm <= 1.0f);
    float factor = 0.9f * powf(err_norm + 1e-10f, -0.2f);
    factor = fminf(10.0f, fmaxf(0.2f, factor));
    if (accept) {
      tcur = tcur + dtc;
#pragma unroll
      for (int c = 0; c < 4; ++c) { yb[c] = ys[c]; k1v[c] = k7v[c]; }  // FSAL
    }
    dt = dtc * factor;
  }

  // ---- out = y @ Wl.T + bl (gate-0 blocks only) ----
  __syncthreads();
#pragma unroll
  for (int c = 0; c < 4; ++c) smem[row * 256 + h0 + c] = yb[c];
  __syncthreads();
  if (gate == 0) {
    const int orow = t >> 6, oc = t & 63;
    float acc = bl[oc];
    for (int k = 0; k < 256; ++k)
      acc = fmaf(smem[orow * 256 + k], Wlt[k * 64 + oc], acc);
    out[(rg * 16 + orow) * 64 + oc] = acc;
  }
}

// ===================== fallback: round-2 kernel (passed) =====================
#define NBLK 32
#define GSTR 772
#define YHF 12352
#define YLF 14400
#define CR0F 16448
#define CZ0F 16704
#define BNF 16960
#define WTRF 17216
#define WTZF 17472
#define WTNF 17728
#define BHNF 17984
#define REDF 18240
#define SBF 18272

__device__ __forceinline__ void eval_fb(
    float* __restrict__ smem,
    const unsigned short* __restrict__ wbh,
    const unsigned short* __restrict__ wbl,
    int lane, int row, int h0, int fo, int nt0,
    const float ys[4], float ts_, float kout[4]) {
  unsigned short h_[4], l_[4];
#pragma unroll
  for (int c = 0; c < 4; ++c) {
    h_[c] = f2bf(ys[c]);
    l_[c] = f2bf(ys[c] - bf2f(h_[c]));
  }
  *(ushort4*)((unsigned short*)(smem + YHF) + fo) =
      make_ushort4(h_[0], h_[1], h_[2], h_[3]);
  *(ushort4*)((unsigned short*)(smem + YLF) + fo) =
      make_ushort4(l_[0], l_[1], l_[2], l_[3]);
  __syncthreads();

  f32x4 ac0 = {0.f, 0.f, 0.f, 0.f};
  f32x4 ac1 = {0.f, 0.f, 0.f, 0.f};
  f32x4 ac2 = {0.f, 0.f, 0.f, 0.f};
  const unsigned short* yh = (const unsigned short*)(smem + YHF);
  const unsigned short* yl = (const unsigned short*)(smem + YLF);
#pragma unroll
  for (int ks2 = 0; ks2 < 8; ++ks2) {
    const bf16x8s ah = *(const bf16x8s*)(yh + (ks2 * 64 + lane) * 8);
    const bf16x8s al = *(const bf16x8s*)(yl + (ks2 * 64 + lane) * 8);
    const bf16x8s bh0 = *(const bf16x8s*)(wbh + (((nt0 + 0) * 8 + ks2) * 64 + lane) * 8);
    const bf16x8s bl0 = *(const bf16x8s*)(wbl + (((nt0 + 0) * 8 + ks2) * 64 + lane) * 8);
    const bf16x8s bh1 = *(const bf16x8s*)(wbh + (((nt0 + 1) * 8 + ks2) * 64 + lane) * 8);
    const bf16x8s bl1 = *(const bf16x8s*)(wbl + (((nt0 + 1) * 8 + ks2) * 64 + lane) * 8);
    const bf16x8s bh2 = *(const bf16x8s*)(wbh + (((nt0 + 2) * 8 + ks2) * 64 + lane) * 8);
    const bf16x8s bl2 = *(const bf16x8s*)(wbl + (((nt0 + 2) * 8 + ks2) * 64 + lane) * 8);
    ac0 = __builtin_amdgcn_mfma_f32_16x16x32_bf16(al, bh0, ac0, 0, 0, 0);
    ac0 = __builtin_amdgcn_mfma_f32_16x16x32_bf16(ah, bl0, ac0, 0, 0, 0);
    ac0 = __builtin_amdgcn_mfma_f32_16x16x32_bf16(ah, bh0, ac0, 0, 0, 0);
    ac1 = __builtin_amdgcn_mfma_f32_16x16x32_bf16(al, bh1, ac1, 0, 0, 0);
    ac1 = __builtin_amdgcn_mfma_f32_16x16x32_bf16(ah, bl1, ac1, 0, 0, 0);
    ac1 = __builtin_amdgcn_mfma_f32_16x16x32_bf16(ah, bh1, ac1, 0, 0, 0);
    ac2 = __builtin_amdgcn_mfma_f32_16x16x32_bf16(al, bh2, ac2, 0, 0, 0);
    ac2 = __builtin_amdgcn_mfma_f32_16x16x32_bf16(ah, bl2, ac2, 0, 0, 0);
    ac2 = __builtin_amdgcn_mfma_f32_16x16x32_bf16(ah, bh2, ac2, 0, 0, 0);
  }
  {
    const int gcol = lane & 15;
    const int gr0 = (lane >> 4) * 4;
#pragma unroll
    for (int j = 0; j < 4; ++j) {
      smem[(gr0 + j) * GSTR + (nt0 + 0) * 16 + gcol] = ac0[j];
      smem[(gr0 + j) * GSTR + (nt0 + 1) * 16 + gcol] = ac1[j];
      smem[(gr0 + j) * GSTR + (nt0 + 2) * 16 + gcol] = ac2[j];
    }
  }
  __syncthreads();

  float gRa[4], gZa[4], gNa[4], cra[4], cza[4], bna[4], wra[4], wza[4], wna[4], bha[4];
  {
    float4 tv;
    tv = *(const float4*)(smem + row * GSTR + h0);       gRa[0]=tv.x; gRa[1]=tv.y; gRa[2]=tv.z; gRa[3]=tv.w;
    tv = *(const float4*)(smem + row * GSTR + 256 + h0); gZa[0]=tv.x; gZa[1]=tv.y; gZa[2]=tv.z; gZa[3]=tv.w;
    tv = *(const float4*)(smem + row * GSTR + 512 + h0); gNa[0]=tv.x; gNa[1]=tv.y; gNa[2]=tv.z; gNa[3]=tv.w;
    tv = *(const float4*)(smem + CR0F + h0); cra[0]=tv.x; cra[1]=tv.y; cra[2]=tv.z; cra[3]=tv.w;
    tv = *(const float4*)(smem + CZ0F + h0); cza[0]=tv.x; cza[1]=tv.y; cza[2]=tv.z; cza[3]=tv.w;
    tv = *(const float4*)(smem + BNF + h0);  bna[0]=tv.x; bna[1]=tv.y; bna[2]=tv.z; bna[3]=tv.w;
    tv = *(const float4*)(smem + WTRF + h0); wra[0]=tv.x; wra[1]=tv.y; wra[2]=tv.z; wra[3]=tv.w;
    tv = *(const float4*)(smem + WTZF + h0); wza[0]=tv.x; wza[1]=tv.y; wza[2]=tv.z; wza[3]=tv.w;
    tv = *(const float4*)(smem + WTNF + h0); wna[0]=tv.x; wna[1]=tv.y; wna[2]=tv.z; wna[3]=tv.w;
    tv = *(const float4*)(smem + BHNF + h0); bha[0]=tv.x; bha[1]=tv.y; bha[2]=tv.z; bha[3]=tv.w;
  }
#pragma unroll
  for (int c = 0; c < 4; ++c) {
    const float rv = sigm(gRa[c] + cra[c] + ts_ * wra[c]);
    const float zv = sigm(gZa[c] + cza[c] + ts_ * wza[c]);
    const float nv = tanh_fast(gNa[c] + bna[c] + ts_ * wna[c] + rv * bha[c]);
    kout[c] = (1.0f - zv) * nv;
  }
}

__global__ void __launch_bounds__(1024)
ode_fb(const float* __restrict__ x,
       const float* __restrict__ tp, int nt,
       const float* __restrict__ bp,
       const float* __restrict__ Wih,
       const float* __restrict__ bih,
       const float* __restrict__ bhh,
       const float* __restrict__ bl,
       const float* __restrict__ ws_f,
       double* __restrict__ partials,
       float* __restrict__ out) {
  extern __shared__ float smem[];
  cg::grid_group grid = cg::this_grid();

  const int rg = blockIdx.x;
  const int t = threadIdx.x;
  const int lane = t & 63;
  const int w = t >> 6;
  const int row = w;
  const int h0 = lane * 4;
  const int nt0 = w * 3;
  const int fo = ((h0 >> 5) * 64 + row + ((h0 >> 3) & 3) * 16) * 8 + (h0 & 7);

  const unsigned short* wbh = (const unsigned short*)ws_f;
  const unsigned short* wbl = ((const unsigned short*)ws_f) + 196608;
  const float* Wpt = ws_f + 196608;
  const float* Wlt = ws_f + 229376;

  const float t0 = tp[0];
  const float t1v = tp[nt - 1];

  if (t < 256) {
    smem[CR0F + t] = bih[t] + bhh[t];
    smem[CZ0F + t] = bih[256 + t] + bhh[256 + t];
    smem[BNF + t]  = bih[512 + t];
    smem[BHNF + t] = bhh[512 + t];
    smem[WTRF + t] = Wih[t * 257 + 256];
    smem[WTZF + t] = Wih[(256 + t) * 257 + 256];
    smem[WTNF + t] = Wih[(512 + t) * 257 + 256];
  }
  smem[t] = x[(rg * 16 + (t >> 7)) * 128 + (t & 127)];
  {
    const int i2 = t + 1024;
    smem[i2] = x[(rg * 16 + (i2 >> 7)) * 128 + (i2 & 127)];
  }
  __syncthreads();

  float yb[4];
  {
    float acc[4] = {0.f, 0.f, 0.f, 0.f};
    for (int k = 0; k < 128; ++k) {
      const float xv = smem[row * 128 + k];
      const float4 wv4 = *(const float4*)(Wpt + k * 256 + h0);
      acc[0] = fmaf(xv, wv4.x, acc[0]);
      acc[1] = fmaf(xv, wv4.y, acc[1]);
      acc[2] = fmaf(xv, wv4.z, acc[2]);
      acc[3] = fmaf(xv, wv4.w, acc[3]);
    }
    const float4 bp4 = *(const float4*)(bp + h0);
    yb[0] = acc[0] + bp4.x; yb[1] = acc[1] + bp4.y;
    yb[2] = acc[2] + bp4.z; yb[3] = acc[3] + bp4.w;
  }

  float tcur = t0;
  float dt = (t1v - t0) * 0.01f + 1e-8f;

  float k1v[4], k2v[4], k3v[4], k4v[4], k5v[4], k6v[4], k7v[4];
  float ys[4];

#pragma unroll
  for (int c = 0; c < 4; ++c) ys[c] = yb[c];
  eval_fb(smem, wbh, wbl, lane, row, h0, fo, nt0, ys, t0, k1v);

  for (int step = 0; step < 64; ++step) {
    if (t1v - tcur <= 1e-6f) break;
    const float dtc = fminf(dt, t1v - tcur);

#pragma unroll
    for (int c = 0; c < 4; ++c) ys[c] = fmaf(dtc * 0.2f, k1v[c], yb[c]);
    eval_fb(smem, wbh, wbl, lane, row, h0, fo, nt0, ys, tcur + dtc * 0.2f, k2v);

#pragma unroll
    for (int c = 0; c < 4; ++c)
      ys[c] = fmaf(dtc, fmaf(F(9.0/40.0), k2v[c], F(3.0/40.0) * k1v[c]), yb[c]);
    eval_fb(smem, wbh, wbl, lane, row, h0, fo, nt0, ys, tcur + dtc * 0.3f, k3v);

#pragma unroll
    for (int c = 0; c < 4; ++c) {
      float in_ = F(44.0/45.0) * k1v[c];
      in_ = fmaf(F(-56.0/15.0), k2v[c], in_);
      in_ = fmaf(F(32.0/9.0), k3v[c], in_);
      ys[c] = fmaf(dtc, in_, yb[c]);
    }
    eval_fb(smem, wbh, wbl, lane, row, h0, fo, nt0, ys, tcur + dtc * 0.8f, k4v);

#pragma unroll
    for (int c = 0; c < 4; ++c) {
      float in_ = F(19372.0/6561.0) * k1v[c];
      in_ = fmaf(F(-25360.0/2187.0), k2v[c], in_);
      in_ = fmaf(F(64448.0/6561.0), k3v[c], in_);
      in_ = fmaf(F(-212.0/729.0), k4v[c], in_);
      ys[c] = fmaf(dtc, in_, yb[c]);
    }
    eval_fb(smem, wbh, wbl, lane, row, h0, fo, nt0, ys, tcur + dtc * F(8.0/9.0), k5v);

#pragma unroll
    for (int c = 0; c < 4; ++c) {
      float in_ = F(9017.0/3168.0) * k1v[c];
      in_ = fmaf(F(-355.0/33.0), k2v[c], in_);
      in_ = fmaf(F(46732.0/5247.0), k3v[c], in_);
      in_ = fmaf(F(49.0/176.0), k4v[c], in_);
      in_ = fmaf(F(-5103.0/18656.0), k5v[c], in_);
      ys[c] = fmaf(dtc, in_, yb[c]);
    }
    eval_fb(smem, wbh, wbl, lane, row, h0, fo, nt0, ys, tcur + dtc, k6v);

#pragma unroll
    for (int c = 0; c < 4; ++c) {
      float in_ = F(35.0/384.0) * k1v[c];
      in_ = fmaf(F(500.0/1113.0), k3v[c], in_);
      in_ = fmaf(F(125.0/192.0), k4v[c], in_);
      in_ = fmaf(F(-2187.0/6784.0), k5v[c], in_);
      in_ = fmaf(F(11.0/84.0), k6v[c], in_);
      ys[c] = fmaf(dtc, in_, yb[c]);
    }
    eval_fb(smem, wbh, wbl, lane, row, h0, fo, nt0, ys, tcur + dtc, k7v);

    double lsum = 0.0;
#pragma unroll
    for (int c = 0; c < 4; ++c) {
      float ev = F(71.0/57600.0) * k1v[c];
      ev = fmaf(F(-71.0/16695.0), k3v[c], ev);
      ev = fmaf(F(71.0/1920.0), k4v[c], ev);
      ev = fmaf(F(-17253.0/339200.0), k5v[c], ev);
      ev = fmaf(F(22.0/525.0), k6v[c], ev);
      ev = fmaf(F(-1.0/40.0), k7v[c], ev);
      ev *= dtc;
      const float sc = 1e-6f + 1e-5f * fmaxf(fabsf(yb[c]), fabsf(ys[c]));
      const float qq = ev / sc;
      lsum += (double)(qq * qq);
    }
    double v = lsum;
#pragma unroll
    for (int d = 1; d < 64; d <<= 1) v += __shfl_xor(v, d, 64);
    if (lane == 0) ((double*)(smem + REDF))[w] = v;
    __syncthreads();
    if (w == 0) {
      double v2 = (lane < 16) ? ((double*)(smem + REDF))[lane] : 0.0;
#pragma unroll
      for (int d = 1; d < 64; d <<= 1) v2 += __shfl_xor(v2, d, 64);
      if (lane == 0) partials[(step & 1) * NBLK + rg] = v2;
    }
    grid.sync();
    if (w == 0) {
      double v3 = (lane < NBLK) ? partials[(step & 1) * NBLK + lane] : 0.0;
#pragma unroll
      for (int d = 1; d < 64; d <<= 1) v3 += __shfl_xor(v3, d, 64);
      if (lane == 0) ((double*)(smem + SBF))[0] = v3;
    }
    __syncthreads();
    const double sb = ((double*)(smem + SBF))[0];
    const float err_norm = sqrtf((float)(sb / 131072.0));
    const bool accept = (err_norm <= 1.0f);
    float factor = 0.9f * powf(err_norm + 1e-10f, -0.2f);
    factor = fminf(10.0f, fmaxf(0.2f, factor));
    if (accept) {
      tcur = tcur + dtc;
#pragma unroll
      for (int c = 0; c < 4; ++c) { yb[c] = ys[c]; k1v[c] = k7v[c]; }
    }
    dt = dtc * factor;
  }

  __syncthreads();
#pragma unroll
  for (int c = 0; c < 4; ++c) smem[row * 256 + h0 + c] = yb[c];
  __syncthreads();
  {
    const int orow = t >> 6, oc = t & 63;
    float acc = bl[oc];
    for (int k = 0; k < 256; ++k)
      acc = fmaf(smem[orow * 256 + k], Wlt[k * 64 + oc], acc);
    out[(rg * 16 + orow) * 64 + oc] = acc;
  }
}

extern "C" void kernel_launch(void* const* d_in, const int* in_sizes, int n_in,
                              void* d_out, int out_size, void* d_ws, size_t ws_size,
                              hipStream_t stream) {
  const float* x   = (const float*)d_in[0];
  const float* tp  = (const float*)d_in[1];
  const float* Wp  = (const float*)d_in[2];
  const float* bp  = (const float*)d_in[3];
  const float* Wih = (const float*)d_in[4];
  const float* bih = (const float*)d_in[5];
  const float* bhh = (const float*)d_in[7];
  const float* Wl  = (const float*)d_in[8];
  const float* bl  = (const float*)d_in[9];
  float* out = (float*)d_out;
  float* ws_f = (float*)d_ws;
  double* partials = (double*)((char*)d_ws + 983040);
  float* gx = (float*)((char*)d_ws + 983552);
  int nt = in_sizes[1];

  hipLaunchKernelGGL(prep_kernel, dim3(960), dim3(256), 0, stream, Wih, Wp, Wl, ws_f);

  if (ws_size >= 4129280ull) {
    const size_t shbytes = 24576;
    hipFuncSetAttribute((const void*)ode_gs,
                        hipFuncAttributeMaxDynamicSharedMemorySize, (int)shbytes);
    void* args[] = { (void*)&x, (void*)&tp, (void*)&nt, (void*)&bp, (void*)&Wih,
                     (void*)&bih, (void*)&bhh, (void*)&bl, (void*)&ws_f,
                     (void*)&gx, (void*)&partials, (void*)&out };
    hipLaunchCooperativeKernel((void*)ode_gs, dim3(96), dim3(1024), args,
                               shbytes, stream);
  } else {
    const size_t shbytes = 73216;
    hipFuncSetAttribute((const void*)ode_fb,
                        hipFuncAttributeMaxDynamicSharedMemorySize, (int)shbytes);
    void* args[] = { (void*)&x, (void*)&tp, (void*)&nt, (void*)&bp, (void*)&Wih,
                     (void*)&bih, (void*)&bhh, (void*)&bl, (void*)&ws_f,
                     (void*)&partials, (void*)&out };
    hipLaunchCooperativeKernel((void*)ode_fb, dim3(NBLK), dim3(1024), args,
                               shbytes, stream);
  }
}

// Round 5
// 594.328 us; speedup vs baseline: 1.5855x; 1.5855x over previous
//
#include <hip/hip_runtime.h>
#include <hip/hip_cooperative_groups.h>
#include <math.h>

namespace cg = cooperative_groups;

// ---------------------------------------------------------------------------
// Round 4: h-split 8-way + per-group flag barriers (no per-eval grid.sync).
//  - 256 blocks x 1024 threads: rg = bid&31 (16 rows), sub = bid>>5 owns
//    h-slice [32*sub, 32*sub+32). Block computes ALL 3 gates for its h-slice
//    (W-slice = 96 cols = 98KB hi+lo per eval -> 0.64us L1 stream), does the
//    GRU nonlinearity locally, publishes k-slice (2KB) to gx[par] via
//    agent-scope atomic stores; 8-arrival flag barrier per row-group
//    (release add + acquire spin); k read back via agent-scope atomic loads.
//  - One grid.sync per STEP (err_norm controller) - round-2 pattern.
//  - Fragments/MFMA chain/controller bit-identical to round 2 (passed,
//    absmax 0.0078125): expect identical trajectory & absmax.
//
// ws layout (bytes):
//   [0,393216)        Wb_hi  ushort[196608] B-frag-packed bf16 hi Wih[:,:256]
//   [393216,786432)   Wb_lo  ushort[196608] bf16 lo
//   [786432,917504)   Wpt    float[32768]
//   [917504,983040)   Wlt    float[16384]
//   [983040,983552)   partials double[2][32]
//   [983552,2032128)  gx     float[2][32][8][16][32] (k exchange)
//   [2032128,2034176) flags  int[32*16] (64B stride per row-group; memset 0)
// Dynamic LDS (floats):
//   [0,2048) yh ushort[4096] | [2048,4096) yl ushort[4096]   (alias: x/y stage)
//   [4096,5696) g_lds[16][100] | [5696,5728) red double[16] | [5728) s_b
// ---------------------------------------------------------------------------

typedef __attribute__((ext_vector_type(8))) short bf16x8s;
typedef __attribute__((ext_vector_type(4))) float f32x4;

#define F(x) ((float)(x))
#define GLDS 4096
#define REDF 5696
#define SBF 5728

static __device__ __forceinline__ unsigned short f2bf(float f) {
  unsigned u = __float_as_uint(f);
  unsigned r = (u + 0x7FFFu + ((u >> 16) & 1u)) >> 16;
  return (unsigned short)r;
}
static __device__ __forceinline__ float bf2f(unsigned short b) {
  return __uint_as_float(((unsigned)b) << 16);
}
static __device__ __forceinline__ float sigm(float x) {
  return 1.0f / (1.0f + __expf(-x));
}
static __device__ __forceinline__ float tanh_fast(float x) {
  float e = __expf(-2.0f * fabsf(x));
  float t = (1.0f - e) / (1.0f + e);
  return copysignf(t, x);
}
static __device__ __forceinline__ void ast(float* p, float v) {
  __hip_atomic_store((unsigned*)p, __float_as_uint(v), __ATOMIC_RELAXED,
                     __HIP_MEMORY_SCOPE_AGENT);
}
static __device__ __forceinline__ float ald(const float* p) {
  return __uint_as_float(__hip_atomic_load((const unsigned*)p,
                                           __ATOMIC_RELAXED,
                                           __HIP_MEMORY_SCOPE_AGENT));
}

__global__ void prep_kernel(const float* __restrict__ Wih,
                            const float* __restrict__ Wp,
                            const float* __restrict__ Wl,
                            float* __restrict__ ws) {
  int i = blockIdx.x * blockDim.x + threadIdx.x;
  if (i < 196608) {
    const int j = i & 7, l = (i >> 3) & 63, ks = (i >> 9) & 7, nt = i >> 12;
    const int c = nt * 16 + (l & 15);          // gate-output column
    const int k = ks * 32 + (l >> 4) * 8 + j;  // k index (same perm as A)
    const float f = Wih[c * 257 + k];
    unsigned short hi = f2bf(f);
    unsigned short lo = f2bf(f - bf2f(hi));
    ((unsigned short*)ws)[i] = hi;
    ((unsigned short*)ws)[196608 + i] = lo;
  } else if (i < 229376) {
    int ii = i - 196608; int hh = ii & 255, k = ii >> 8;
    ws[i] = Wp[hh * 128 + k];
  } else if (i < 245760) {
    int ii = i - 229376; int c = ii & 63, k = ii >> 6;
    ws[i] = Wl[c * 256 + k];
  }
}

// One f-eval. Thread-owned ys[4] (row=w, h0=lane*4) -> kout[4] (same owner).
__device__ __forceinline__ void eval_hs(
    float* __restrict__ smem,
    const unsigned short* __restrict__ wbh,
    const unsigned short* __restrict__ wbl,
    float* __restrict__ gx, int* __restrict__ flag,
    int rg, int sub, int lane, int w, int h0, int fo, int t, int ec,
    const float ys[4], float ts_,
    float cr0, float cz0, float bn_, float wtr, float wtz, float wtn,
    float bhn, float kout[4]) {
  // ---- pack ys -> A-frags (bf16 hi/lo), identical to round 2 ----
  unsigned short h_[4], l_[4];
#pragma unroll
  for (int c = 0; c < 4; ++c) {
    h_[c] = f2bf(ys[c]);
    l_[c] = f2bf(ys[c] - bf2f(h_[c]));
  }
  unsigned short* yhb = (unsigned short*)smem;
  *(ushort4*)(yhb + fo) = make_ushort4(h_[0], h_[1], h_[2], h_[3]);
  *(ushort4*)(yhb + 4096 + fo) = make_ushort4(l_[0], l_[1], l_[2], l_[3]);
  __syncthreads();

  // ---- MFMA: waves 0..5 each one 16x16 g-tile of this block's h-slice ----
  if (w < 6) {
    f32x4 ac = {0.f, 0.f, 0.f, 0.f};
    const int ntg = (w >> 1) * 16 + sub * 2 + (w & 1);  // global n-tile
    const unsigned short* yh = yhb;
    const unsigned short* yl = yhb + 4096;
#pragma unroll
    for (int ks2 = 0; ks2 < 8; ++ks2) {
      const bf16x8s ah = *(const bf16x8s*)(yh + (ks2 * 64 + lane) * 8);
      const bf16x8s al = *(const bf16x8s*)(yl + (ks2 * 64 + lane) * 8);
      const bf16x8s bh = *(const bf16x8s*)(wbh + ((ntg * 8 + ks2) * 64 + lane) * 8);
      const bf16x8s blo = *(const bf16x8s*)(wbl + ((ntg * 8 + ks2) * 64 + lane) * 8);
      ac = __builtin_amdgcn_mfma_f32_16x16x32_bf16(al, bh, ac, 0, 0, 0);
      ac = __builtin_amdgcn_mfma_f32_16x16x32_bf16(ah, blo, ac, 0, 0, 0);
      ac = __builtin_amdgcn_mfma_f32_16x16x32_bf16(ah, bh, ac, 0, 0, 0);
    }
    // C: col=lane&15, row=(lane>>4)*4+j -> g_lds[row][w*16+col] (stride 100)
    const int gcol = w * 16 + (lane & 15);
    const int gr0 = (lane >> 4) * 4;
#pragma unroll
    for (int j = 0; j < 4; ++j) smem[GLDS + (gr0 + j) * 100 + gcol] = ac[j];
  }
  __syncthreads();

  // ---- GRU nonlinearity for (row=t>>5, hl=t&31); publish k-slice ----
  if (t < 512) {
    const int row = t >> 5, hl = t & 31;
    const float gR = smem[GLDS + row * 100 + hl];
    const float gZ = smem[GLDS + row * 100 + 32 + hl];
    const float gN = smem[GLDS + row * 100 + 64 + hl];
    const float rv = sigm(gR + cr0 + ts_ * wtr);
    const float zv = sigm(gZ + cz0 + ts_ * wtz);
    const float nv = tanh_fast(gN + bn_ + ts_ * wtn + rv * bhn);
    const float kv = (1.0f - zv) * nv;
    ast(gx + (size_t)(((ec & 1) * 32 + rg) * 8 + sub) * 512 + row * 32 + hl, kv);
  }
  __syncthreads();  // drains vmcnt: k stores globally visible before arrive

  // ---- 8-block group barrier (release add / acquire spin) ----
  if (t == 0) {
    __hip_atomic_fetch_add(flag, 1, __ATOMIC_RELEASE, __HIP_MEMORY_SCOPE_AGENT);
    const int tgt = 8 * (ec + 1);
    while (__hip_atomic_load(flag, __ATOMIC_ACQUIRE,
                             __HIP_MEMORY_SCOPE_AGENT) < tgt)
      __builtin_amdgcn_s_sleep(1);
  }
  __syncthreads();

  // ---- read back owned k elements (row=w, h0..h0+3) ----
  const int subsrc = h0 >> 5;
  const float* kbase = gx + (size_t)(((ec & 1) * 32 + rg) * 8 + subsrc) * 512 +
                       w * 32 + (h0 & 31);
#pragma unroll
  for (int c = 0; c < 4; ++c) kout[c] = ald(kbase + c);
}

__global__ void __launch_bounds__(1024)
ode_hs(const float* __restrict__ x,
       const float* __restrict__ tp, int nt,
       const float* __restrict__ bp,
       const float* __restrict__ Wih,
       const float* __restrict__ bih,
       const float* __restrict__ bhh,
       const float* __restrict__ bl,
       const float* __restrict__ ws_f,
       float* __restrict__ gx,
       int* __restrict__ flags,
       double* __restrict__ partials,
       float* __restrict__ out) {
  extern __shared__ float smem[];
  cg::grid_group grid = cg::this_grid();

  const int bid = blockIdx.x;
  const int rg = bid & 31;      // rows rg*16 .. rg*16+15
  const int sub = bid >> 5;     // h-slice [32*sub, 32*sub+32)
  const int t = threadIdx.x;
  const int lane = t & 63;
  const int w = t >> 6;         // wave = owned row
  const int h0 = lane * 4;      // owned hidden indices h0..h0+3
  const int fo = ((h0 >> 5) * 64 + w + ((h0 >> 3) & 3) * 16) * 8 + (h0 & 7);
  int* flag = flags + rg * 16;

  const unsigned short* wbh = (const unsigned short*)ws_f;
  const unsigned short* wbl = ((const unsigned short*)ws_f) + 196608;
  const float* Wpt = ws_f + 196608;
  const float* Wlt = ws_f + 229376;

  const float t0 = tp[0];
  const float t1v = tp[nt - 1];

  // ---- per-thread nonlinearity consts for global h = sub*32 + (t&31) ----
  float cr0 = 0.f, cz0 = 0.f, bn_ = 0.f, wtr = 0.f, wtz = 0.f, wtn = 0.f,
        bhn = 0.f;
  if (t < 512) {
    const int gh = sub * 32 + (t & 31);
    cr0 = bih[gh] + bhh[gh];
    cz0 = bih[256 + gh] + bhh[256 + gh];
    bn_ = bih[512 + gh];
    bhn = bhh[512 + gh];
    wtr = Wih[gh * 257 + 256];
    wtz = Wih[(256 + gh) * 257 + 256];
    wtn = Wih[(512 + gh) * 257 + 256];
  }

  // ---- stage x (16 rows x 128) into frag area (aliased) ----
  smem[t] = x[(rg * 16 + (t >> 7)) * 128 + (t & 127)];
  {
    const int i2 = t + 1024;
    smem[i2] = x[(rg * 16 + (i2 >> 7)) * 128 + (i2 & 127)];
  }
  __syncthreads();

  // ---- h0 = x @ Wp.T + bp (identical op order to round 2) ----
  float yb[4];
  {
    float acc[4] = {0.f, 0.f, 0.f, 0.f};
    for (int k = 0; k < 128; ++k) {
      const float xv = smem[w * 128 + k];
      const float4 wv4 = *(const float4*)(Wpt + k * 256 + h0);
      acc[0] = fmaf(xv, wv4.x, acc[0]);
      acc[1] = fmaf(xv, wv4.y, acc[1]);
      acc[2] = fmaf(xv, wv4.z, acc[2]);
      acc[3] = fmaf(xv, wv4.w, acc[3]);
    }
    const float4 bp4 = *(const float4*)(bp + h0);
    yb[0] = acc[0] + bp4.x; yb[1] = acc[1] + bp4.y;
    yb[2] = acc[2] + bp4.z; yb[3] = acc[3] + bp4.w;
  }
  __syncthreads();  // x-staging about to be overwritten by A-frags

  float tcur = t0;
  float dt = (t1v - t0) * 0.01f + 1e-8f;
  int ec = 0;

  float k1v[4], k2v[4], k3v[4], k4v[4], k5v[4], k6v[4], k7v[4];
  float ys[4];

#pragma unroll
  for (int c = 0; c < 4; ++c) ys[c] = yb[c];
  eval_hs(smem, wbh, wbl, gx, flag, rg, sub, lane, w, h0, fo, t, ec, ys, t0,
          cr0, cz0, bn_, wtr, wtz, wtn, bhn, k1v);
  ++ec;

  for (int step = 0; step < 64; ++step) {
    if (t1v - tcur <= 1e-6f) break;  // exact: ref freezes state once done
    const float dtc = fminf(dt, t1v - tcur);

#pragma unroll
    for (int c = 0; c < 4; ++c) ys[c] = fmaf(dtc * 0.2f, k1v[c], yb[c]);
    eval_hs(smem, wbh, wbl, gx, flag, rg, sub, lane, w, h0, fo, t, ec, ys,
            tcur + dtc * 0.2f, cr0, cz0, bn_, wtr, wtz, wtn, bhn, k2v);
    ++ec;

#pragma unroll
    for (int c = 0; c < 4; ++c)
      ys[c] = fmaf(dtc, fmaf(F(9.0/40.0), k2v[c], F(3.0/40.0) * k1v[c]), yb[c]);
    eval_hs(smem, wbh, wbl, gx, flag, rg, sub, lane, w, h0, fo, t, ec, ys,
            tcur + dtc * 0.3f, cr0, cz0, bn_, wtr, wtz, wtn, bhn, k3v);
    ++ec;

#pragma unroll
    for (int c = 0; c < 4; ++c) {
      float in_ = F(44.0/45.0) * k1v[c];
      in_ = fmaf(F(-56.0/15.0), k2v[c], in_);
      in_ = fmaf(F(32.0/9.0), k3v[c], in_);
      ys[c] = fmaf(dtc, in_, yb[c]);
    }
    eval_hs(smem, wbh, wbl, gx, flag, rg, sub, lane, w, h0, fo, t, ec, ys,
            tcur + dtc * 0.8f, cr0, cz0, bn_, wtr, wtz, wtn, bhn, k4v);
    ++ec;

#pragma unroll
    for (int c = 0; c < 4; ++c) {
      float in_ = F(19372.0/6561.0) * k1v[c];
      in_ = fmaf(F(-25360.0/2187.0), k2v[c], in_);
      in_ = fmaf(F(64448.0/6561.0), k3v[c], in_);
      in_ = fmaf(F(-212.0/729.0), k4v[c], in_);
      ys[c] = fmaf(dtc, in_, yb[c]);
    }
    eval_hs(smem, wbh, wbl, gx, flag, rg, sub, lane, w, h0, fo, t, ec, ys,
            tcur + dtc * F(8.0/9.0), cr0, cz0, bn_, wtr, wtz, wtn, bhn, k5v);
    ++ec;

#pragma unroll
    for (int c = 0; c < 4; ++c) {
      float in_ = F(9017.0/3168.0) * k1v[c];
      in_ = fmaf(F(-355.0/33.0), k2v[c], in_);
      in_ = fmaf(F(46732.0/5247.0), k3v[c], in_);
      in_ = fmaf(F(49.0/176.0), k4v[c], in_);
      in_ = fmaf(F(-5103.0/18656.0), k5v[c], in_);
      ys[c] = fmaf(dtc, in_, yb[c]);
    }
    eval_hs(smem, wbh, wbl, gx, flag, rg, sub, lane, w, h0, fo, t, ec, ys,
            tcur + dtc, cr0, cz0, bn_, wtr, wtz, wtn, bhn, k6v);
    ++ec;

    // y5 into ys, k7 = f(t+dt, y5)
#pragma unroll
    for (int c = 0; c < 4; ++c) {
      float in_ = F(35.0/384.0) * k1v[c];
      in_ = fmaf(F(500.0/1113.0), k3v[c], in_);
      in_ = fmaf(F(125.0/192.0), k4v[c], in_);
      in_ = fmaf(F(-2187.0/6784.0), k5v[c], in_);
      in_ = fmaf(F(11.0/84.0), k6v[c], in_);
      ys[c] = fmaf(dtc, in_, yb[c]);
    }
    eval_hs(smem, wbh, wbl, gx, flag, rg, sub, lane, w, h0, fo, t, ec, ys,
            tcur + dtc, cr0, cz0, bn_, wtr, wtz, wtn, bhn, k7v);
    ++ec;

    // ---- error estimate over thread-owned elements (identical) ----
    double lsum = 0.0;
#pragma unroll
    for (int c = 0; c < 4; ++c) {
      float ev = F(71.0/57600.0) * k1v[c];
      ev = fmaf(F(-71.0/16695.0), k3v[c], ev);
      ev = fmaf(F(71.0/1920.0), k4v[c], ev);
      ev = fmaf(F(-17253.0/339200.0), k5v[c], ev);
      ev = fmaf(F(22.0/525.0), k6v[c], ev);
      ev = fmaf(F(-1.0/40.0), k7v[c], ev);
      ev *= dtc;
      const float sc = 1e-6f + 1e-5f * fmaxf(fabsf(yb[c]), fabsf(ys[c]));
      const float qq = ev / sc;
      lsum += (double)(qq * qq);
    }
    double v = lsum;
#pragma unroll
    for (int d = 1; d < 64; d <<= 1) v += __shfl_xor(v, d, 64);
    if (lane == 0) ((double*)(smem + REDF))[w] = v;
    __syncthreads();
    if (w == 0 && sub == 0) {
      double v2 = (lane < 16) ? ((double*)(smem + REDF))[lane] : 0.0;
#pragma unroll
      for (int d = 1; d < 64; d <<= 1) v2 += __shfl_xor(v2, d, 64);
      if (lane == 0) partials[(step & 1) * 32 + rg] = v2;
    }
    grid.sync();
    if (w == 0) {
      double v3 = (lane < 32) ? partials[(step & 1) * 32 + lane] : 0.0;
#pragma unroll
      for (int d = 1; d < 64; d <<= 1) v3 += __shfl_xor(v3, d, 64);
      if (lane == 0) ((double*)(smem + SBF))[0] = v3;
    }
    __syncthreads();
    const double sb = ((double*)(smem + SBF))[0];
    const float err_norm = sqrtf((float)(sb / 131072.0));
    const bool accept = (err_norm <= 1.0f);
    float factor = 0.9f * powf(err_norm + 1e-10f, -0.2f);
    factor = fminf(10.0f, fmaxf(0.2f, factor));
    if (accept) {
      tcur = tcur + dtc;
#pragma unroll
      for (int c = 0; c < 4; ++c) { yb[c] = ys[c]; k1v[c] = k7v[c]; }  // FSAL
    }
    dt = dtc * factor;
  }

  // ---- out = y @ Wl.T + bl (sub==0 blocks only) ----
  __syncthreads();
#pragma unroll
  for (int c = 0; c < 4; ++c) smem[w * 256 + h0 + c] = yb[c];
  __syncthreads();
  if (sub == 0) {
    const int orow = t >> 6, oc = t & 63;
    float acc = bl[oc];
    for (int k = 0; k < 256; ++k)
      acc = fmaf(smem[orow * 256 + k], Wlt[k * 64 + oc], acc);
    out[(rg * 16 + orow) * 64 + oc] = acc;
  }
}

extern "C" void kernel_launch(void* const* d_in, const int* in_sizes, int n_in,
                              void* d_out, int out_size, void* d_ws, size_t ws_size,
                              hipStream_t stream) {
  const float* x   = (const float*)d_in[0];
  const float* tp  = (const float*)d_in[1];
  const float* Wp  = (const float*)d_in[2];
  const float* bp  = (const float*)d_in[3];
  const float* Wih = (const float*)d_in[4];
  const float* bih = (const float*)d_in[5];
  const float* bhh = (const float*)d_in[7];
  const float* Wl  = (const float*)d_in[8];
  const float* bl  = (const float*)d_in[9];
  float* out = (float*)d_out;
  float* ws_f = (float*)d_ws;
  double* partials = (double*)((char*)d_ws + 983040);
  float* gx = (float*)((char*)d_ws + 983552);
  int* flags = (int*)((char*)d_ws + 2032128);
  int nt = in_sizes[1];

  hipLaunchKernelGGL(prep_kernel, dim3(960), dim3(256), 0, stream, Wih, Wp, Wl, ws_f);
  hipMemsetAsync(flags, 0, 2048, stream);  // flag barrier counters start at 0

  const size_t shbytes = 23040;
  hipFuncSetAttribute((const void*)ode_hs,
                      hipFuncAttributeMaxDynamicSharedMemorySize, (int)shbytes);

  void* args[] = { (void*)&x, (void*)&tp, (void*)&nt, (void*)&bp, (void*)&Wih,
                   (void*)&bih, (void*)&bhh, (void*)&bl, (void*)&ws_f,
                   (void*)&gx, (void*)&flags, (void*)&partials, (void*)&out };
  hipLaunchCooperativeKernel((void*)ode_hs, dim3(256), dim3(1024), args,
                             shbytes, stream);
}

// Round 6
// 442.469 us; speedup vs baseline: 2.1297x; 1.3432x over previous
//
#include <hip/hip_runtime.h>
#include <math.h>

// ---------------------------------------------------------------------------
// Round 5: B-in-registers + flag barriers everywhere (no grid.sync at all).
//  - 256 blocks x 512 threads (8 waves). rg = bid&31 owns 16 rows; sub = bid>>5
//    owns h-slice [32*sub,32*sub+32). Thread owns rows {w, w+8} x h0=lane*4..+3.
//  - Waves 0..5 hold their n-tile's full B (hi+lo, 8 ksteps) in 64 VGPRs,
//    loaded ONCE in the prologue: zero W memory traffic in the eval loop.
//  - Per eval: pack A-frags (LDS) -> 24 MFMA -> g_lds -> nonlinearity ->
//    publish 2KB k-slice -> 8-block flag barrier -> readback. (round-4 flow)
//  - Per step: err partial per rg (redundant, deterministic) published by
//    sub==0; 32-arrival global flag barrier replaces grid.sync (~12us -> ~1us).
//  - Per-element math bit-identical to rounds 2/4 (same fragments, same MFMA
//    chain, same controller formulas). Only the err-sum tree shape changed
//    (double-precision, ~1e-16) -> same trajectory expected.
//
// ws layout (bytes):
//   [0,393216)        Wb_hi  ushort[196608] B-frag-packed bf16 hi Wih[:,:256]
//   [393216,786432)   Wb_lo  ushort[196608] bf16 lo
//   [786432,917504)   Wpt    float[32768]
//   [917504,983040)   Wlt    float[16384]
//   [983040,983552)   partials double[2][32]
//   [983552,2032128)  gx     float[2][32][8][16][32] (k exchange)
//   [2032128,2034176) flags  int[32*16] (eval barriers, 64B stride per rg)
//   [2034176,2034180) gcnt   int (step barrier)            [memset 0 at launch]
// Dynamic LDS (floats):
//   [0,2048) yh ushort[4096] | [2048,4096) yl ushort[4096] (alias: x/y stage)
//   [4096,5696) g_lds[16][100] | [5696,5712) red double[8] | [5712) s_b double
// ---------------------------------------------------------------------------

typedef __attribute__((ext_vector_type(8))) short bf16x8s;
typedef __attribute__((ext_vector_type(4))) float f32x4;

#define F(x) ((float)(x))
#define GLDS 4096
#define REDF 5696
#define SBF 5712

static __device__ __forceinline__ unsigned short f2bf(float f) {
  unsigned u = __float_as_uint(f);
  unsigned r = (u + 0x7FFFu + ((u >> 16) & 1u)) >> 16;
  return (unsigned short)r;
}
static __device__ __forceinline__ float bf2f(unsigned short b) {
  return __uint_as_float(((unsigned)b) << 16);
}
static __device__ __forceinline__ float sigm(float x) {
  return 1.0f / (1.0f + __expf(-x));
}
static __device__ __forceinline__ float tanh_fast(float x) {
  float e = __expf(-2.0f * fabsf(x));
  float t = (1.0f - e) / (1.0f + e);
  return copysignf(t, x);
}
static __device__ __forceinline__ void ast(float* p, float v) {
  __hip_atomic_store((unsigned*)p, __float_as_uint(v), __ATOMIC_RELAXED,
                     __HIP_MEMORY_SCOPE_AGENT);
}
static __device__ __forceinline__ unsigned long long ald8(const float* p) {
  return __hip_atomic_load((const unsigned long long*)p, __ATOMIC_RELAXED,
                           __HIP_MEMORY_SCOPE_AGENT);
}
static __device__ __forceinline__ void astd(double* p, double v) {
  __hip_atomic_store((unsigned long long*)p, (unsigned long long)__double_as_longlong(v),
                     __ATOMIC_RELAXED, __HIP_MEMORY_SCOPE_AGENT);
}
static __device__ __forceinline__ double aldd(const double* p) {
  return __longlong_as_double((long long)__hip_atomic_load(
      (const unsigned long long*)p, __ATOMIC_RELAXED, __HIP_MEMORY_SCOPE_AGENT));
}

__global__ void prep_kernel(const float* __restrict__ Wih,
                            const float* __restrict__ Wp,
                            const float* __restrict__ Wl,
                            float* __restrict__ ws) {
  int i = blockIdx.x * blockDim.x + threadIdx.x;
  if (i < 196608) {
    const int j = i & 7, l = (i >> 3) & 63, ks = (i >> 9) & 7, nt = i >> 12;
    const int c = nt * 16 + (l & 15);          // gate-output column
    const int k = ks * 32 + (l >> 4) * 8 + j;  // k index (same perm as A)
    const float f = Wih[c * 257 + k];
    unsigned short hi = f2bf(f);
    unsigned short lo = f2bf(f - bf2f(hi));
    ((unsigned short*)ws)[i] = hi;
    ((unsigned short*)ws)[196608 + i] = lo;
  } else if (i < 229376) {
    int ii = i - 196608; int hh = ii & 255, k = ii >> 8;
    ws[i] = Wp[hh * 128 + k];
  } else if (i < 245760) {
    int ii = i - 229376; int c = ii & 63, k = ii >> 6;
    ws[i] = Wl[c * 256 + k];
  }
}

// One f-eval. Thread owns rows {w, w+8} x h0..h0+3: ys[8] -> kout[8].
__device__ __forceinline__ void eval2(
    float* __restrict__ smem, float* __restrict__ gx, int* __restrict__ flag,
    const bf16x8s (&bhr)[8], const bf16x8s (&blr)[8],
    int rg, int sub, int lane, int w, int h0, int fo0, int fo1, int t, int ec,
    const float (&ys)[8], float ts_,
    float cr0, float cz0, float bn_, float wtr, float wtz, float wtn,
    float bhn, float (&kout)[8]) {
  // ---- pack ys -> A-frags (bf16 hi/lo), identical values to round 2 ----
  unsigned short h_[8], l_[8];
#pragma unroll
  for (int c = 0; c < 8; ++c) {
    h_[c] = f2bf(ys[c]);
    l_[c] = f2bf(ys[c] - bf2f(h_[c]));
  }
  unsigned short* yhb = (unsigned short*)smem;
  *(ushort4*)(yhb + fo0) = make_ushort4(h_[0], h_[1], h_[2], h_[3]);
  *(ushort4*)(yhb + fo1) = make_ushort4(h_[4], h_[5], h_[6], h_[7]);
  *(ushort4*)(yhb + 4096 + fo0) = make_ushort4(l_[0], l_[1], l_[2], l_[3]);
  *(ushort4*)(yhb + 4096 + fo1) = make_ushort4(l_[4], l_[5], l_[6], l_[7]);
  __syncthreads();

  // ---- MFMA: waves 0..5, B entirely in registers ----
  if (w < 6) {
    f32x4 ac = {0.f, 0.f, 0.f, 0.f};
    const unsigned short* yh = yhb;
    const unsigned short* yl = yhb + 4096;
#pragma unroll
    for (int ks2 = 0; ks2 < 8; ++ks2) {
      const bf16x8s ah = *(const bf16x8s*)(yh + (ks2 * 64 + lane) * 8);
      const bf16x8s al = *(const bf16x8s*)(yl + (ks2 * 64 + lane) * 8);
      ac = __builtin_amdgcn_mfma_f32_16x16x32_bf16(al, bhr[ks2], ac, 0, 0, 0);
      ac = __builtin_amdgcn_mfma_f32_16x16x32_bf16(ah, blr[ks2], ac, 0, 0, 0);
      ac = __builtin_amdgcn_mfma_f32_16x16x32_bf16(ah, bhr[ks2], ac, 0, 0, 0);
    }
    // C: col=lane&15, row=(lane>>4)*4+j -> g_lds[row][w*16+col] (stride 100)
    const int gcol = w * 16 + (lane & 15);
    const int gr0 = (lane >> 4) * 4;
#pragma unroll
    for (int j = 0; j < 4; ++j) smem[GLDS + (gr0 + j) * 100 + gcol] = ac[j];
  }
  __syncthreads();

  // ---- GRU nonlinearity for (row=t>>5, hl=t&31); publish k-slice ----
  {
    const int row = t >> 5, hl = t & 31;
    const float gR = smem[GLDS + row * 100 + hl];
    const float gZ = smem[GLDS + row * 100 + 32 + hl];
    const float gN = smem[GLDS + row * 100 + 64 + hl];
    const float rv = sigm(gR + cr0 + ts_ * wtr);
    const float zv = sigm(gZ + cz0 + ts_ * wtz);
    const float nv = tanh_fast(gN + bn_ + ts_ * wtn + rv * bhn);
    const float kv = (1.0f - zv) * nv;
    ast(gx + (size_t)(((ec & 1) * 32 + rg) * 8 + sub) * 512 + row * 32 + hl, kv);
  }
  __syncthreads();  // drains vmcnt: k stores issued before arrive

  // ---- 8-block group barrier (release add / acquire spin) ----
  if (t == 0) {
    __hip_atomic_fetch_add(flag, 1, __ATOMIC_RELEASE, __HIP_MEMORY_SCOPE_AGENT);
    const int tgt = 8 * (ec + 1);
    while (__hip_atomic_load(flag, __ATOMIC_ACQUIRE,
                             __HIP_MEMORY_SCOPE_AGENT) < tgt)
      __builtin_amdgcn_s_sleep(1);
  }
  __syncthreads();

  // ---- read back owned k elements: rows w, w+8 at h0..h0+3 ----
  const int subsrc = h0 >> 5;
  const float* kb = gx + (size_t)(((ec & 1) * 32 + rg) * 8 + subsrc) * 512 +
                    (h0 & 31);
  unsigned long long q0 = ald8(kb + w * 32);
  unsigned long long q1 = ald8(kb + w * 32 + 2);
  unsigned long long q2 = ald8(kb + (w + 8) * 32);
  unsigned long long q3 = ald8(kb + (w + 8) * 32 + 2);
  kout[0] = __uint_as_float((unsigned)q0);
  kout[1] = __uint_as_float((unsigned)(q0 >> 32));
  kout[2] = __uint_as_float((unsigned)q1);
  kout[3] = __uint_as_float((unsigned)(q1 >> 32));
  kout[4] = __uint_as_float((unsigned)q2);
  kout[5] = __uint_as_float((unsigned)(q2 >> 32));
  kout[6] = __uint_as_float((unsigned)q3);
  kout[7] = __uint_as_float((unsigned)(q3 >> 32));
}

__global__ void __launch_bounds__(512)
ode_hs2(const float* __restrict__ x,
        const float* __restrict__ tp, int nt,
        const float* __restrict__ bp,
        const float* __restrict__ Wih,
        const float* __restrict__ bih,
        const float* __restrict__ bhh,
        const float* __restrict__ bl,
        const float* __restrict__ ws_f,
        float* __restrict__ gx,
        int* __restrict__ flags,
        double* __restrict__ partials,
        float* __restrict__ out) {
  extern __shared__ float smem[];

  const int bid = blockIdx.x;
  const int rg = bid & 31;      // rows rg*16 .. rg*16+15
  const int sub = bid >> 5;     // h-slice [32*sub, 32*sub+32)
  const int t = threadIdx.x;
  const int lane = t & 63;
  const int w = t >> 6;         // wave 0..7; thread owns rows {w, w+8}
  const int h0 = lane * 4;      // owned hidden indices h0..h0+3
  const int fo0 = ((h0 >> 5) * 64 + w + ((h0 >> 3) & 3) * 16) * 8 + (h0 & 7);
  const int fo1 = ((h0 >> 5) * 64 + (w + 8) + ((h0 >> 3) & 3) * 16) * 8 + (h0 & 7);
  int* flag = flags + rg * 16;
  int* gcnt = flags + 512;

  const unsigned short* wbh = (const unsigned short*)ws_f;
  const unsigned short* wbl = ((const unsigned short*)ws_f) + 196608;
  const float* Wpt = ws_f + 196608;
  const float* Wlt = ws_f + 229376;

  const float t0 = tp[0];
  const float t1v = tp[nt - 1];

  // ---- B (this wave's n-tile, all 8 ksteps, hi+lo) -> 64 VGPRs, ONCE ----
  bf16x8s bhr[8], blr[8];
  if (w < 6) {
    const int ntg = (w >> 1) * 16 + sub * 2 + (w & 1);  // global n-tile
#pragma unroll
    for (int ks2 = 0; ks2 < 8; ++ks2) {
      bhr[ks2] = *(const bf16x8s*)(wbh + ((ntg * 8 + ks2) * 64 + lane) * 8);
      blr[ks2] = *(const bf16x8s*)(wbl + ((ntg * 8 + ks2) * 64 + lane) * 8);
    }
  } else {
#pragma unroll
    for (int ks2 = 0; ks2 < 8; ++ks2) {
      bhr[ks2] = bf16x8s{0, 0, 0, 0, 0, 0, 0, 0};
      blr[ks2] = bf16x8s{0, 0, 0, 0, 0, 0, 0, 0};
    }
  }

  // ---- per-thread nonlinearity consts for global h = sub*32 + (t&31) ----
  const int gh = sub * 32 + (t & 31);
  const float cr0 = bih[gh] + bhh[gh];
  const float cz0 = bih[256 + gh] + bhh[256 + gh];
  const float bn_ = bih[512 + gh];
  const float bhn = bhh[512 + gh];
  const float wtr = Wih[gh * 257 + 256];
  const float wtz = Wih[(256 + gh) * 257 + 256];
  const float wtn = Wih[(512 + gh) * 257 + 256];

  // ---- stage x (16 rows x 128) into frag area (aliased) ----
  for (int i = t; i < 2048; i += 512)
    smem[i] = x[(rg * 16 + (i >> 7)) * 128 + (i & 127)];
  __syncthreads();

  // ---- h0 = x @ Wp.T + bp (identical per-element op order) ----
  float yb[8];
  {
    float acc[8] = {0.f, 0.f, 0.f, 0.f, 0.f, 0.f, 0.f, 0.f};
    for (int k = 0; k < 128; ++k) {
      const float xv0 = smem[w * 128 + k];
      const float xv1 = smem[(w + 8) * 128 + k];
      const float4 wv4 = *(const float4*)(Wpt + k * 256 + h0);
      acc[0] = fmaf(xv0, wv4.x, acc[0]);
      acc[1] = fmaf(xv0, wv4.y, acc[1]);
      acc[2] = fmaf(xv0, wv4.z, acc[2]);
      acc[3] = fmaf(xv0, wv4.w, acc[3]);
      acc[4] = fmaf(xv1, wv4.x, acc[4]);
      acc[5] = fmaf(xv1, wv4.y, acc[5]);
      acc[6] = fmaf(xv1, wv4.z, acc[6]);
      acc[7] = fmaf(xv1, wv4.w, acc[7]);
    }
    const float4 bp4 = *(const float4*)(bp + h0);
    yb[0] = acc[0] + bp4.x; yb[1] = acc[1] + bp4.y;
    yb[2] = acc[2] + bp4.z; yb[3] = acc[3] + bp4.w;
    yb[4] = acc[4] + bp4.x; yb[5] = acc[5] + bp4.y;
    yb[6] = acc[6] + bp4.z; yb[7] = acc[7] + bp4.w;
  }
  __syncthreads();  // x-staging about to be overwritten by A-frags

  float tcur = t0;
  float dt = (t1v - t0) * 0.01f + 1e-8f;
  int ec = 0;

  float k1v[8], k2v[8], k3v[8], k4v[8], k5v[8], k6v[8], k7v[8];
  float ys[8];

#pragma unroll
  for (int c = 0; c < 8; ++c) ys[c] = yb[c];
  eval2(smem, gx, flag, bhr, blr, rg, sub, lane, w, h0, fo0, fo1, t, ec, ys,
        t0, cr0, cz0, bn_, wtr, wtz, wtn, bhn, k1v);
  ++ec;

  for (int step = 0; step < 64; ++step) {
    if (t1v - tcur <= 1e-6f) break;  // exact: ref freezes state once done
    const float dtc = fminf(dt, t1v - tcur);

#pragma unroll
    for (int c = 0; c < 8; ++c) ys[c] = fmaf(dtc * 0.2f, k1v[c], yb[c]);
    eval2(smem, gx, flag, bhr, blr, rg, sub, lane, w, h0, fo0, fo1, t, ec, ys,
          tcur + dtc * 0.2f, cr0, cz0, bn_, wtr, wtz, wtn, bhn, k2v);
    ++ec;

#pragma unroll
    for (int c = 0; c < 8; ++c)
      ys[c] = fmaf(dtc, fmaf(F(9.0/40.0), k2v[c], F(3.0/40.0) * k1v[c]), yb[c]);
    eval2(smem, gx, flag, bhr, blr, rg, sub, lane, w, h0, fo0, fo1, t, ec, ys,
          tcur + dtc * 0.3f, cr0, cz0, bn_, wtr, wtz, wtn, bhn, k3v);
    ++ec;

#pragma unroll
    for (int c = 0; c < 8; ++c) {
      float in_ = F(44.0/45.0) * k1v[c];
      in_ = fmaf(F(-56.0/15.0), k2v[c], in_);
      in_ = fmaf(F(32.0/9.0), k3v[c], in_);
      ys[c] = fmaf(dtc, in_, yb[c]);
    }
    eval2(smem, gx, flag, bhr, blr, rg, sub, lane, w, h0, fo0, fo1, t, ec, ys,
          tcur + dtc * 0.8f, cr0, cz0, bn_, wtr, wtz, wtn, bhn, k4v);
    ++ec;

#pragma unroll
    for (int c = 0; c < 8; ++c) {
      float in_ = F(19372.0/6561.0) * k1v[c];
      in_ = fmaf(F(-25360.0/2187.0), k2v[c], in_);
      in_ = fmaf(F(64448.0/6561.0), k3v[c], in_);
      in_ = fmaf(F(-212.0/729.0), k4v[c], in_);
      ys[c] = fmaf(dtc, in_, yb[c]);
    }
    eval2(smem, gx, flag, bhr, blr, rg, sub, lane, w, h0, fo0, fo1, t, ec, ys,
          tcur + dtc * F(8.0/9.0), cr0, cz0, bn_, wtr, wtz, wtn, bhn, k5v);
    ++ec;

#pragma unroll
    for (int c = 0; c < 8; ++c) {
      float in_ = F(9017.0/3168.0) * k1v[c];
      in_ = fmaf(F(-355.0/33.0), k2v[c], in_);
      in_ = fmaf(F(46732.0/5247.0), k3v[c], in_);
      in_ = fmaf(F(49.0/176.0), k4v[c], in_);
      in_ = fmaf(F(-5103.0/18656.0), k5v[c], in_);
      ys[c] = fmaf(dtc, in_, yb[c]);
    }
    eval2(smem, gx, flag, bhr, blr, rg, sub, lane, w, h0, fo0, fo1, t, ec, ys,
          tcur + dtc, cr0, cz0, bn_, wtr, wtz, wtn, bhn, k6v);
    ++ec;

    // y5 into ys, k7 = f(t+dt, y5)
#pragma unroll
    for (int c = 0; c < 8; ++c) {
      float in_ = F(35.0/384.0) * k1v[c];
      in_ = fmaf(F(500.0/1113.0), k3v[c], in_);
      in_ = fmaf(F(125.0/192.0), k4v[c], in_);
      in_ = fmaf(F(-2187.0/6784.0), k5v[c], in_);
      in_ = fmaf(F(11.0/84.0), k6v[c], in_);
      ys[c] = fmaf(dtc, in_, yb[c]);
    }
    eval2(smem, gx, flag, bhr, blr, rg, sub, lane, w, h0, fo0, fo1, t, ec, ys,
          tcur + dtc, cr0, cz0, bn_, wtr, wtz, wtn, bhn, k7v);
    ++ec;

    // ---- error estimate over thread-owned elements (identical formulas) ----
    double lsum = 0.0;
#pragma unroll
    for (int c = 0; c < 8; ++c) {
      float ev = F(71.0/57600.0) * k1v[c];
      ev = fmaf(F(-71.0/16695.0), k3v[c], ev);
      ev = fmaf(F(71.0/1920.0), k4v[c], ev);
      ev = fmaf(F(-17253.0/339200.0), k5v[c], ev);
      ev = fmaf(F(22.0/525.0), k6v[c], ev);
      ev = fmaf(F(-1.0/40.0), k7v[c], ev);
      ev *= dtc;
      const float sc = 1e-6f + 1e-5f * fmaxf(fabsf(yb[c]), fabsf(ys[c]));
      const float qq = ev / sc;
      lsum += (double)(qq * qq);
    }
    double v = lsum;
#pragma unroll
    for (int d = 1; d < 64; d <<= 1) v += __shfl_xor(v, d, 64);
    if (lane == 0) ((double*)(smem + REDF))[w] = v;
    __syncthreads();
    if (w == 0 && sub == 0) {
      double v2 = (lane < 8) ? ((double*)(smem + REDF))[lane] : 0.0;
#pragma unroll
      for (int d = 1; d < 64; d <<= 1) v2 += __shfl_xor(v2, d, 64);
      if (lane == 0) {
        astd(&partials[(step & 1) * 32 + rg], v2);
        __hip_atomic_fetch_add(gcnt, 1, __ATOMIC_RELEASE,
                               __HIP_MEMORY_SCOPE_AGENT);
      }
    }
    // ---- 32-arrival global step barrier (replaces grid.sync) ----
    if (t == 0) {
      const int tgt = 32 * (step + 1);
      while (__hip_atomic_load(gcnt, __ATOMIC_ACQUIRE,
                               __HIP_MEMORY_SCOPE_AGENT) < tgt)
        __builtin_amdgcn_s_sleep(1);
    }
    __syncthreads();
    if (w == 0) {
      double v3 = (lane < 32) ? aldd(&partials[(step & 1) * 32 + lane]) : 0.0;
#pragma unroll
      for (int d = 1; d < 64; d <<= 1) v3 += __shfl_xor(v3, d, 64);
      if (lane == 0) ((double*)(smem + SBF))[0] = v3;
    }
    __syncthreads();
    const double sb = ((double*)(smem + SBF))[0];
    const float err_norm = sqrtf((float)(sb / 131072.0));
    const bool accept = (err_norm <= 1.0f);
    float factor = 0.9f * powf(err_norm + 1e-10f, -0.2f);
    factor = fminf(10.0f, fmaxf(0.2f, factor));
    if (accept) {
      tcur = tcur + dtc;
#pragma unroll
      for (int c = 0; c < 8; ++c) { yb[c] = ys[c]; k1v[c] = k7v[c]; }  // FSAL
    }
    dt = dtc * factor;
  }

  // ---- out = y @ Wl.T + bl (sub==0 blocks only) ----
  __syncthreads();
#pragma unroll
  for (int c = 0; c < 4; ++c) {
    smem[w * 256 + h0 + c] = yb[c];
    smem[(w + 8) * 256 + h0 + c] = yb[4 + c];
  }
  __syncthreads();
  if (sub == 0) {
    const int oc = t & 63;
#pragma unroll
    for (int rr = 0; rr < 2; ++rr) {
      const int orow = (t >> 6) + rr * 8;
      float acc = bl[oc];
      for (int k = 0; k < 256; ++k)
        acc = fmaf(smem[orow * 256 + k], Wlt[k * 64 + oc], acc);
      out[(rg * 16 + orow) * 64 + oc] = acc;
    }
  }
}

extern "C" void kernel_launch(void* const* d_in, const int* in_sizes, int n_in,
                              void* d_out, int out_size, void* d_ws, size_t ws_size,
                              hipStream_t stream) {
  const float* x   = (const float*)d_in[0];
  const float* tp  = (const float*)d_in[1];
  const float* Wp  = (const float*)d_in[2];
  const float* bp  = (const float*)d_in[3];
  const float* Wih = (const float*)d_in[4];
  const float* bih = (const float*)d_in[5];
  const float* bhh = (const float*)d_in[7];
  const float* Wl  = (const float*)d_in[8];
  const float* bl  = (const float*)d_in[9];
  float* out = (float*)d_out;
  float* ws_f = (float*)d_ws;
  double* partials = (double*)((char*)d_ws + 983040);
  float* gx = (float*)((char*)d_ws + 983552);
  int* flags = (int*)((char*)d_ws + 2032128);
  int nt = in_sizes[1];

  hipLaunchKernelGGL(prep_kernel, dim3(960), dim3(256), 0, stream, Wih, Wp, Wl, ws_f);
  hipMemsetAsync(flags, 0, 4096, stream);  // eval flags + step counter -> 0

  const size_t shbytes = 23040;
  hipFuncSetAttribute((const void*)ode_hs2,
                      hipFuncAttributeMaxDynamicSharedMemorySize, (int)shbytes);

  void* args[] = { (void*)&x, (void*)&tp, (void*)&nt, (void*)&bp, (void*)&Wih,
                   (void*)&bih, (void*)&bhh, (void*)&bl, (void*)&ws_f,
                   (void*)&gx, (void*)&flags, (void*)&partials, (void*)&out };
  hipLaunchCooperativeKernel((void*)ode_hs2, dim3(256), dim3(512), args,
                             shbytes, stream);
}

// Round 7
// 300.056 us; speedup vs baseline: 3.1405x; 1.4746x over previous
//
#include <hip/hip_runtime.h>
#include <math.h>

// ---------------------------------------------------------------------------
// Round 6: self-validating 64-bit packets replace flag barriers entirely.
//  - 256 blocks x 512 threads. rg = bid&31 owns 16 rows; sub = bid>>5 owns
//    h-slice [32*sub,32*sub+32). B (hi+lo) in registers (waves 0..5).
//  - Per eval: pack A-frags (XOR-swizzled LDS, kills 16-way write conflict)
//    -> 24 MFMA -> g_lds -> nonlinearity -> publish k as (seq|bits) u64
//    packets (1 relaxed agent atomic store/thread) -> poll own 8 packets
//    until seq matches. ONE remote leg instead of three (r5: store->flag
//    RMW+spin->load). No flags, no grid.sync anywhere.
//  - Per step: each block publishes its OWN slice err partial (local k
//    history) overlapping the k7 packet latency; all blocks poll 256
//    partial-pairs (double split into 2 tagged u64s) and reduce with one
//    fixed tree -> identical controller everywhere. Tree reshape vs r5
//    perturbs err_norm by ~1e-16 (inert).
//  - WAR/deadlock safety of 2-slot parity buffers: producer at eval e
//    overwrites slot e&1 only after polling ALL seq-e packets, which
//    requires every sibling to have published e-1, hence consumed e-2.
//  - Packet regions zeroed via hipMemsetAsync each launch (graph-safe,
//    deterministic across replays).
//
// ws layout (bytes):
//   [0,393216)        Wb_hi  ushort[196608] B-frag-packed bf16 hi Wih[:,:256]
//   [393216,786432)   Wb_lo  ushort[196608] bf16 lo
//   [786432,917504)   Wpt    float[32768]
//   [917504,983040)   Wlt    float[16384]
//   [1048576,3145728) kpk    u64[2][32][8][16][32]  k packets (seq|bits)
//   [3145728,3153920) ppk    u64[2][32][8][2]       err-partial packets
// Dynamic LDS (floats):
//   [0,4096)  A-frags: yh bytes [0,8192) + yl bytes [8192,16384), XOR-swizzled
//             (alias: x-staging at init, y at end)
//   [4096,5696) g_lds[16][100] | [5696,5712) red double[8] | [5712) s_b double
// ---------------------------------------------------------------------------

typedef __attribute__((ext_vector_type(8))) short bf16x8s;
typedef __attribute__((ext_vector_type(4))) float f32x4;

#define F(x) ((float)(x))
#define GLDS 4096
#define REDF 5696
#define SBF 5712
// byte-offset XOR swizzle within each 8KB A-frag region (write & read sides)
#define SWZ(b) ((b) ^ ((((b) >> 8) & 7) << 4))

static __device__ __forceinline__ unsigned short f2bf(float f) {
  unsigned u = __float_as_uint(f);
  unsigned r = (u + 0x7FFFu + ((u >> 16) & 1u)) >> 16;
  return (unsigned short)r;
}
static __device__ __forceinline__ float bf2f(unsigned short b) {
  return __uint_as_float(((unsigned)b) << 16);
}
static __device__ __forceinline__ float sigm(float x) {
  return 1.0f / (1.0f + __expf(-x));
}
static __device__ __forceinline__ float tanh_fast(float x) {
  float e = __expf(-2.0f * fabsf(x));
  float t = (1.0f - e) / (1.0f + e);
  return copysignf(t, x);
}
static __device__ __forceinline__ void pub64(unsigned long long* p,
                                             unsigned long long v) {
  __hip_atomic_store(p, v, __ATOMIC_RELAXED, __HIP_MEMORY_SCOPE_AGENT);
}
static __device__ __forceinline__ unsigned long long ld64(
    const unsigned long long* p) {
  return __hip_atomic_load(p, __ATOMIC_RELAXED, __HIP_MEMORY_SCOPE_AGENT);
}

__global__ void prep_kernel(const float* __restrict__ Wih,
                            const float* __restrict__ Wp,
                            const float* __restrict__ Wl,
                            float* __restrict__ ws) {
  int i = blockIdx.x * blockDim.x + threadIdx.x;
  if (i < 196608) {
    const int j = i & 7, l = (i >> 3) & 63, ks = (i >> 9) & 7, nt = i >> 12;
    const int c = nt * 16 + (l & 15);          // gate-output column
    const int k = ks * 32 + (l >> 4) * 8 + j;  // k index (same perm as A)
    const float f = Wih[c * 257 + k];
    unsigned short hi = f2bf(f);
    unsigned short lo = f2bf(f - bf2f(hi));
    ((unsigned short*)ws)[i] = hi;
    ((unsigned short*)ws)[196608 + i] = lo;
  } else if (i < 229376) {
    int ii = i - 196608; int hh = ii & 255, k = ii >> 8;
    ws[i] = Wp[hh * 128 + k];
  } else if (i < 245760) {
    int ii = i - 229376; int c = ii & 63, k = ii >> 6;
    ws[i] = Wl[c * 256 + k];
  }
}

// Front half of one f-eval: pack -> MFMA -> nonlin -> publish k packets.
// Returns this thread's slice-k value (row=t>>5, hl=t&31) in ks_out.
__device__ __forceinline__ void eval_front(
    float* __restrict__ smem, unsigned long long* __restrict__ kpk,
    const bf16x8s (&bhr)[8], const bf16x8s (&blr)[8],
    int rg, int sub, int lane, int w, int fo0, int fo1, int t, int ec,
    const float (&ys)[8], float ts_,
    float cr0, float cz0, float bn_, float wtr, float wtz, float wtn,
    float bhn, float& ks_out) {
  // ---- pack ys -> A-frags (bf16 hi/lo), swizzled locations ----
  unsigned short h_[8], l_[8];
#pragma unroll
  for (int c = 0; c < 8; ++c) {
    h_[c] = f2bf(ys[c]);
    l_[c] = f2bf(ys[c] - bf2f(h_[c]));
  }
  char* yB = (char*)smem;
  *(ushort4*)(yB + SWZ(2 * fo0)) = make_ushort4(h_[0], h_[1], h_[2], h_[3]);
  *(ushort4*)(yB + SWZ(2 * fo1)) = make_ushort4(h_[4], h_[5], h_[6], h_[7]);
  *(ushort4*)(yB + 8192 + SWZ(2 * fo0)) = make_ushort4(l_[0], l_[1], l_[2], l_[3]);
  *(ushort4*)(yB + 8192 + SWZ(2 * fo1)) = make_ushort4(l_[4], l_[5], l_[6], l_[7]);
  __syncthreads();

  // ---- MFMA: waves 0..5, B in registers, swizzled A reads ----
  if (w < 6) {
    f32x4 ac = {0.f, 0.f, 0.f, 0.f};
#pragma unroll
    for (int ks2 = 0; ks2 < 8; ++ks2) {
      const int rb = SWZ(16 * (ks2 * 64 + lane));
      const bf16x8s ah = *(const bf16x8s*)(yB + rb);
      const bf16x8s al = *(const bf16x8s*)(yB + 8192 + rb);
      ac = __builtin_amdgcn_mfma_f32_16x16x32_bf16(al, bhr[ks2], ac, 0, 0, 0);
      ac = __builtin_amdgcn_mfma_f32_16x16x32_bf16(ah, blr[ks2], ac, 0, 0, 0);
      ac = __builtin_amdgcn_mfma_f32_16x16x32_bf16(ah, bhr[ks2], ac, 0, 0, 0);
    }
    // C: col=lane&15, row=(lane>>4)*4+j -> g_lds[row][w*16+col] (stride 100)
    const int gcol = w * 16 + (lane & 15);
    const int gr0 = (lane >> 4) * 4;
#pragma unroll
    for (int j = 0; j < 4; ++j) smem[GLDS + (gr0 + j) * 100 + gcol] = ac[j];
  }
  __syncthreads();

  // ---- GRU nonlinearity for (row=t>>5, hl=t&31); publish packet ----
  {
    const int row = t >> 5, hl = t & 31;
    const float gR = smem[GLDS + row * 100 + hl];
    const float gZ = smem[GLDS + row * 100 + 32 + hl];
    const float gN = smem[GLDS + row * 100 + 64 + hl];
    const float rv = sigm(gR + cr0 + ts_ * wtr);
    const float zv = sigm(gZ + cz0 + ts_ * wtz);
    const float nv = tanh_fast(gN + bn_ + ts_ * wtn + rv * bhn);
    const float kv = (1.0f - zv) * nv;
    ks_out = kv;
    pub64(kpk + ((size_t)((ec & 1) * 32 + rg) * 8 + sub) * 512 + row * 32 + hl,
          ((unsigned long long)(unsigned)(ec + 1) << 32) | __float_as_uint(kv));
  }
}

// Poll own 8 k packets (rows w, w+8 at h0..h0+3) for this eval.
__device__ __forceinline__ void eval_poll(
    const unsigned long long* __restrict__ kpk,
    int rg, int w, int h0, int ec, float (&kout)[8]) {
  const int subsrc = h0 >> 5;
  const unsigned long long* kb =
      kpk + ((size_t)((ec & 1) * 32 + rg) * 8 + subsrc) * 512 + (h0 & 31);
  const unsigned tag = (unsigned)(ec + 1);
  unsigned long long q[8];
  for (;;) {
    bool ok = true;
#pragma unroll
    for (int i = 0; i < 8; ++i) {
      const int rr = (i >> 2) * 8 + w;  // rows w, w+8
      q[i] = ld64(kb + rr * 32 + (i & 3));
      ok &= ((unsigned)(q[i] >> 32) == tag);
    }
    if (ok) break;
    __builtin_amdgcn_s_sleep(1);
  }
#pragma unroll
  for (int i = 0; i < 8; ++i) kout[i] = __uint_as_float((unsigned)q[i]);
}

#define EVAL(KOUT, KS, TS)                                                     \
  do {                                                                         \
    eval_front(smem, kpk, bhr, blr, rg, sub, lane, w, fo0, fo1, t, ec, ys,     \
               (TS), cr0, cz0, bn_, wtr, wtz, wtn, bhn, KS);                   \
    eval_poll(kpk, rg, w, h0, ec, KOUT);                                       \
    ++ec;                                                                      \
  } while (0)

__global__ void __launch_bounds__(512)
ode_pk(const float* __restrict__ x,
       const float* __restrict__ tp, int nt,
       const float* __restrict__ bp,
       const float* __restrict__ Wih,
       const float* __restrict__ bih,
       const float* __restrict__ bhh,
       const float* __restrict__ bl,
       const float* __restrict__ ws_f,
       unsigned long long* __restrict__ kpk,
       unsigned long long* __restrict__ ppk,
       float* __restrict__ out) {
  extern __shared__ float smem[];

  const int bid = blockIdx.x;
  const int rg = bid & 31;      // rows rg*16 .. rg*16+15
  const int sub = bid >> 5;     // h-slice [32*sub, 32*sub+32)
  const int t = threadIdx.x;
  const int lane = t & 63;
  const int w = t >> 6;         // wave 0..7; thread owns rows {w, w+8}
  const int h0 = lane * 4;      // owned hidden indices h0..h0+3
  const int fo0 = ((h0 >> 5) * 64 + w + ((h0 >> 3) & 3) * 16) * 8 + (h0 & 7);
  const int fo1 = ((h0 >> 5) * 64 + (w + 8) + ((h0 >> 3) & 3) * 16) * 8 + (h0 & 7);

  const unsigned short* wbh = (const unsigned short*)ws_f;
  const unsigned short* wbl = ((const unsigned short*)ws_f) + 196608;
  const float* Wpt = ws_f + 196608;
  const float* Wlt = ws_f + 229376;

  const float t0 = tp[0];
  const float t1v = tp[nt - 1];

  // ---- B (this wave's n-tile, all 8 ksteps, hi+lo) -> regs, ONCE ----
  bf16x8s bhr[8], blr[8];
  if (w < 6) {
    const int ntg = (w >> 1) * 16 + sub * 2 + (w & 1);  // global n-tile
#pragma unroll
    for (int ks2 = 0; ks2 < 8; ++ks2) {
      bhr[ks2] = *(const bf16x8s*)(wbh + ((ntg * 8 + ks2) * 64 + lane) * 8);
      blr[ks2] = *(const bf16x8s*)(wbl + ((ntg * 8 + ks2) * 64 + lane) * 8);
    }
  } else {
#pragma unroll
    for (int ks2 = 0; ks2 < 8; ++ks2) {
      bhr[ks2] = bf16x8s{0, 0, 0, 0, 0, 0, 0, 0};
      blr[ks2] = bf16x8s{0, 0, 0, 0, 0, 0, 0, 0};
    }
  }

  // ---- per-thread nonlinearity consts for global h = sub*32 + (t&31) ----
  const int gh = sub * 32 + (t & 31);
  const float cr0 = bih[gh] + bhh[gh];
  const float cz0 = bih[256 + gh] + bhh[256 + gh];
  const float bn_ = bih[512 + gh];
  const float bhn = bhh[512 + gh];
  const float wtr = Wih[gh * 257 + 256];
  const float wtz = Wih[(256 + gh) * 257 + 256];
  const float wtn = Wih[(512 + gh) * 257 + 256];

  // ---- stage x (16 rows x 128) into frag area (aliased) ----
  for (int i = t; i < 2048; i += 512)
    smem[i] = x[(rg * 16 + (i >> 7)) * 128 + (i & 127)];
  __syncthreads();

  // ---- h0 = x @ Wp.T + bp: owner elements (rows w,w+8 x h0..h0+3) ----
  float yb[8];
  {
    float acc[8] = {0.f, 0.f, 0.f, 0.f, 0.f, 0.f, 0.f, 0.f};
    for (int k = 0; k < 128; ++k) {
      const float xv0 = smem[w * 128 + k];
      const float xv1 = smem[(w + 8) * 128 + k];
      const float4 wv4 = *(const float4*)(Wpt + k * 256 + h0);
      acc[0] = fmaf(xv0, wv4.x, acc[0]);
      acc[1] = fmaf(xv0, wv4.y, acc[1]);
      acc[2] = fmaf(xv0, wv4.z, acc[2]);
      acc[3] = fmaf(xv0, wv4.w, acc[3]);
      acc[4] = fmaf(xv1, wv4.x, acc[4]);
      acc[5] = fmaf(xv1, wv4.y, acc[5]);
      acc[6] = fmaf(xv1, wv4.z, acc[6]);
      acc[7] = fmaf(xv1, wv4.w, acc[7]);
    }
    const float4 bp4 = *(const float4*)(bp + h0);
    yb[0] = acc[0] + bp4.x; yb[1] = acc[1] + bp4.y;
    yb[2] = acc[2] + bp4.z; yb[3] = acc[3] + bp4.w;
    yb[4] = acc[4] + bp4.x; yb[5] = acc[5] + bp4.y;
    yb[6] = acc[6] + bp4.z; yb[7] = acc[7] + bp4.w;
  }
  // ---- h0 for this thread's SLICE element (row=t>>5, h=gh): bitwise same
  //      scalar chain as the owner's computation of that element ----
  float ybs;
  {
    const int row_s = t >> 5;
    float accs = 0.f;
    for (int k = 0; k < 128; ++k)
      accs = fmaf(smem[row_s * 128 + k], Wpt[k * 256 + gh], accs);
    ybs = accs + bp[gh];
  }
  __syncthreads();  // x-staging about to be overwritten by A-frags

  float tcur = t0;
  float dt = (t1v - t0) * 0.01f + 1e-8f;
  int ec = 0;

  float k1v[8], k2v[8], k3v[8], k4v[8], k5v[8], k6v[8], k7v[8];
  float ys[8];
  float k1s, k2s, k3s, k4s, k5s, k6s, k7s;

#pragma unroll
  for (int c = 0; c < 8; ++c) ys[c] = yb[c];
  EVAL(k1v, k1s, t0);  // k1; FSAL afterwards

  for (int step = 0; step < 64; ++step) {
    if (t1v - tcur <= 1e-6f) break;  // exact: ref freezes state once done
    const float dtc = fminf(dt, t1v - tcur);

#pragma unroll
    for (int c = 0; c < 8; ++c) ys[c] = fmaf(dtc * 0.2f, k1v[c], yb[c]);
    EVAL(k2v, k2s, tcur + dtc * 0.2f);

#pragma unroll
    for (int c = 0; c < 8; ++c)
      ys[c] = fmaf(dtc, fmaf(F(9.0/40.0), k2v[c], F(3.0/40.0) * k1v[c]), yb[c]);
    EVAL(k3v, k3s, tcur + dtc * 0.3f);

#pragma unroll
    for (int c = 0; c < 8; ++c) {
      float in_ = F(44.0/45.0) * k1v[c];
      in_ = fmaf(F(-56.0/15.0), k2v[c], in_);
      in_ = fmaf(F(32.0/9.0), k3v[c], in_);
      ys[c] = fmaf(dtc, in_, yb[c]);
    }
    EVAL(k4v, k4s, tcur + dtc * 0.8f);

#pragma unroll
    for (int c = 0; c < 8; ++c) {
      float in_ = F(19372.0/6561.0) * k1v[c];
      in_ = fmaf(F(-25360.0/2187.0), k2v[c], in_);
      in_ = fmaf(F(64448.0/6561.0), k3v[c], in_);
      in_ = fmaf(F(-212.0/729.0), k4v[c], in_);
      ys[c] = fmaf(dtc, in_, yb[c]);
    }
    EVAL(k5v, k5s, tcur + dtc * F(8.0/9.0));

#pragma unroll
    for (int c = 0; c < 8; ++c) {
      float in_ = F(9017.0/3168.0) * k1v[c];
      in_ = fmaf(F(-355.0/33.0), k2v[c], in_);
      in_ = fmaf(F(46732.0/5247.0), k3v[c], in_);
      in_ = fmaf(F(49.0/176.0), k4v[c], in_);
      in_ = fmaf(F(-5103.0/18656.0), k5v[c], in_);
      ys[c] = fmaf(dtc, in_, yb[c]);
    }
    EVAL(k6v, k6s, tcur + dtc);

    // y5 into ys, then k7 = f(t+dt, y5) -- front only; err partial is
    // published from LOCAL slice history BEFORE polling k7 (overlap).
#pragma unroll
    for (int c = 0; c < 8; ++c) {
      float in_ = F(35.0/384.0) * k1v[c];
      in_ = fmaf(F(500.0/1113.0), k3v[c], in_);
      in_ = fmaf(F(125.0/192.0), k4v[c], in_);
      in_ = fmaf(F(-2187.0/6784.0), k5v[c], in_);
      in_ = fmaf(F(11.0/84.0), k6v[c], in_);
      ys[c] = fmaf(dtc, in_, yb[c]);
    }
    eval_front(smem, kpk, bhr, blr, rg, sub, lane, w, fo0, fo1, t, ec, ys,
               tcur + dtc, cr0, cz0, bn_, wtr, wtz, wtn, bhn, k7s);

    // ---- slice y5 + err element (local; bitwise same chains) ----
    float y5s;
    {
      float in_ = F(35.0/384.0) * k1s;
      in_ = fmaf(F(500.0/1113.0), k3s, in_);
      in_ = fmaf(F(125.0/192.0), k4s, in_);
      in_ = fmaf(F(-2187.0/6784.0), k5s, in_);
      in_ = fmaf(F(11.0/84.0), k6s, in_);
      y5s = fmaf(dtc, in_, ybs);
    }
    double lsum;
    {
      float ev = F(71.0/57600.0) * k1s;
      ev = fmaf(F(-71.0/16695.0), k3s, ev);
      ev = fmaf(F(71.0/1920.0), k4s, ev);
      ev = fmaf(F(-17253.0/339200.0), k5s, ev);
      ev = fmaf(F(22.0/525.0), k6s, ev);
      ev = fmaf(F(-1.0/40.0), k7s, ev);
      ev *= dtc;
      const float sc = 1e-6f + 1e-5f * fmaxf(fabsf(ybs), fabsf(y5s));
      const float qq = ev / sc;
      lsum = (double)(qq * qq);
    }
    // block slice-partial: wave butterfly -> 8 wave sums -> t0 serial sum
    double v = lsum;
#pragma unroll
    for (int d = 1; d < 64; d <<= 1) v += __shfl_xor(v, d, 64);
    if (lane == 0) ((double*)(smem + REDF))[w] = v;
    __syncthreads();
    if (t == 0) {
      double s = ((double*)(smem + REDF))[0];
#pragma unroll
      for (int i = 1; i < 8; ++i) s += ((double*)(smem + REDF))[i];
      const unsigned long long bits =
          (unsigned long long)__double_as_longlong(s);
      const unsigned long long tg =
          ((unsigned long long)(unsigned)(step + 1)) << 32;
      unsigned long long* pb = ppk + ((size_t)((step & 1) * 32 + rg) * 8 + sub) * 2;
      pub64(pb + 0, tg | (unsigned)(bits & 0xffffffffull));
      pub64(pb + 1, tg | (unsigned)(bits >> 32));
    }
    // ---- poll k7 packets (overlapped with partial propagation) ----
    eval_poll(kpk, rg, w, h0, ec, k7v);
    ++ec;
    __syncthreads();  // red[] reuse below

    // ---- poll all 256 slice partials; fixed-tree global sum ----
    double myp = 0.0;
    if (t < 256) {
      const int prg = t >> 3, psub = t & 7;
      const unsigned long long* pb =
          ppk + ((size_t)((step & 1) * 32 + prg) * 8 + psub) * 2;
      const unsigned tg = (unsigned)(step + 1);
      unsigned long long a, b;
      for (;;) {
        a = ld64(pb + 0);
        b = ld64(pb + 1);
        if (((unsigned)(a >> 32) == tg) && ((unsigned)(b >> 32) == tg)) break;
        __builtin_amdgcn_s_sleep(1);
      }
      myp = __longlong_as_double(
          (long long)(((unsigned long long)(unsigned)b << 32) |
                      (unsigned)(a & 0xffffffffull)));
    }
    double v3 = myp;
#pragma unroll
    for (int d = 1; d < 64; d <<= 1) v3 += __shfl_xor(v3, d, 64);
    if (lane == 0) ((double*)(smem + REDF))[w] = v3;
    __syncthreads();
    if (t == 0) {
      double s = ((double*)(smem + REDF))[0];
#pragma unroll
      for (int i = 1; i < 8; ++i) s += ((double*)(smem + REDF))[i];
      ((double*)(smem + SBF))[0] = s;
    }
    __syncthreads();
    const double sb = ((double*)(smem + SBF))[0];
    const float err_norm = sqrtf((float)(sb / 131072.0));
    const bool accept = (err_norm <= 1.0f);
    float factor = 0.9f * powf(err_norm + 1e-10f, -0.2f);
    factor = fminf(10.0f, fmaxf(0.2f, factor));
    if (accept) {
      tcur = tcur + dtc;
#pragma unroll
      for (int c = 0; c < 8; ++c) { yb[c] = ys[c]; k1v[c] = k7v[c]; }  // FSAL
      ybs = y5s; k1s = k7s;
    }
    dt = dtc * factor;
  }

  // ---- out = y @ Wl.T + bl (sub==0 blocks only) ----
  __syncthreads();
#pragma unroll
  for (int c = 0; c < 4; ++c) {
    smem[w * 256 + h0 + c] = yb[c];
    smem[(w + 8) * 256 + h0 + c] = yb[4 + c];
  }
  __syncthreads();
  if (sub == 0) {
    const int oc = t & 63;
#pragma unroll
    for (int rr = 0; rr < 2; ++rr) {
      const int orow = (t >> 6) + rr * 8;
      float acc = bl[oc];
      for (int k = 0; k < 256; ++k)
        acc = fmaf(smem[orow * 256 + k], Wlt[k * 64 + oc], acc);
      out[(rg * 16 + orow) * 64 + oc] = acc;
    }
  }
}

extern "C" void kernel_launch(void* const* d_in, const int* in_sizes, int n_in,
                              void* d_out, int out_size, void* d_ws, size_t ws_size,
                              hipStream_t stream) {
  const float* x   = (const float*)d_in[0];
  const float* tp  = (const float*)d_in[1];
  const float* Wp  = (const float*)d_in[2];
  const float* bp  = (const float*)d_in[3];
  const float* Wih = (const float*)d_in[4];
  const float* bih = (const float*)d_in[5];
  const float* bhh = (const float*)d_in[7];
  const float* Wl  = (const float*)d_in[8];
  const float* bl  = (const float*)d_in[9];
  float* out = (float*)d_out;
  float* ws_f = (float*)d_ws;
  unsigned long long* kpk = (unsigned long long*)((char*)d_ws + 1048576);
  unsigned long long* ppk = (unsigned long long*)((char*)d_ws + 3145728);
  int nt = in_sizes[1];

  hipLaunchKernelGGL(prep_kernel, dim3(960), dim3(256), 0, stream, Wih, Wp, Wl, ws_f);
  // zero packet regions every launch: deterministic across graph replays
  hipMemsetAsync((char*)d_ws + 1048576, 0, 2105344, stream);

  const size_t shbytes = 23040;
  hipFuncSetAttribute((const void*)ode_pk,
                      hipFuncAttributeMaxDynamicSharedMemorySize, (int)shbytes);

  void* args[] = { (void*)&x, (void*)&tp, (void*)&nt, (void*)&bp, (void*)&Wih,
                   (void*)&bih, (void*)&bhh, (void*)&bl, (void*)&ws_f,
                   (void*)&kpk, (void*)&ppk, (void*)&out };
  hipLaunchCooperativeKernel((void*)ode_pk, dim3(256), dim3(512), args,
                             shbytes, stream);
}